// Round 11
// baseline (133.508 us; speedup 1.0000x reference)
//
#include <hip/hip_runtime.h>
#include <stdint.h>
#include <math.h>

typedef unsigned short u16;
typedef _Float16 f16;
typedef __attribute__((ext_vector_type(4))) float f32x4;
typedef __attribute__((ext_vector_type(8))) f16 h8;
typedef __attribute__((ext_vector_type(4))) f16 h4;
typedef __attribute__((ext_vector_type(2))) f16 h2;
typedef __attribute__((ext_vector_type(2))) __fp16 fp16x2;
typedef __attribute__((ext_vector_type(2))) unsigned int u32x2;
typedef __attribute__((ext_vector_type(4))) unsigned int u32x4;
typedef __attribute__((ext_vector_type(4))) unsigned short u16x4;
typedef __attribute__((ext_vector_type(8))) unsigned short u16x8;

typedef const __attribute__((address_space(1))) u16 gas_u16;
typedef __attribute__((address_space(3))) u16 las_u16;

#define MFMA32(a,b,c) __builtin_amdgcn_mfma_f32_16x16x32_f16((a),(b),(c),0,0,0)
#define MFMA16(a,b,c) __builtin_amdgcn_mfma_f32_16x16x16f16((a),(b),(c),0,0,0)

__device__ __forceinline__ float h2f(u16 h){ f16 x; __builtin_memcpy(&x,&h,2); return (float)x; }
__device__ __forceinline__ u16 f2h(float f){ f16 x = (f16)f; u16 u; __builtin_memcpy(&u,&x,2); return u; }

__device__ __forceinline__ float fast_exp2(float x){
#if __has_builtin(__builtin_amdgcn_exp2f)
  return __builtin_amdgcn_exp2f(x);
#else
  return exp2f(x);
#endif
}

// pack two f32 -> two f16 in one v_cvt_pkrtz; bit-cast to _Float16 vector type
__device__ __forceinline__ h2 pkrtz(float a, float b){
  fp16x2 t = __builtin_amdgcn_cvt_pkrtz(a, b);
  h2 r; __builtin_memcpy(&r, &t, 4);
  return r;
}

// ---------------- fused fp32 -> fp16 convert (x, w1, w2 in one launch) ----------------
#define NA4 1572864
#define NB4 442368
#define NC4 147456
__global__ __launch_bounds__(256) void cvt3_kernel(
    const float* __restrict__ a, u16* __restrict__ da,
    const float* __restrict__ b, u16* __restrict__ db,
    const float* __restrict__ c, u16* __restrict__ dc)
{
  int i = blockIdx.x*256 + threadIdx.x;
  const float* s; u16* d; int off;
  if (i < NA4)            { s = a; d = da; off = i; }
  else if (i < NA4+NB4)   { s = b; d = db; off = i - NA4; }
  else if (i < NA4+NB4+NC4){ s = c; d = dc; off = i - NA4 - NB4; }
  else return;
  f32x4 v = ((const f32x4*)s)[off];
  u16x4 o;
  o[0]=f2h(v[0]); o[1]=f2h(v[1]); o[2]=f2h(v[2]); o[3]=f2h(v[3]);
  ((u16x4*)d)[off] = o;
}

// ---------------- fp16 GEMM, C = A(M x 768) * B(N x 768)^T + bias ----------------
// TRIPLE-buffered T4 pipeline at BK=32, prefetch depth 2 (the untested variable:
// R8/R10 showed depth-1 configs all plateau at 52-54us regardless of occupancy).
// Prologue stages tiles 0,1; iter t issues tile t+2 then waits vmcnt(8) -> tiles
// t+1,t+2 (8 loads) stay in flight across the barrier, ~800 cyc latency cover.
// WAR safe: buffer (t+2)%3 == (t-1)%3, reads drained at iter t-1's lgkmcnt+barrier.
// LDS 48KB -> 3 blocks/CU. Conflict-free swizzle (round-9-verified 0 conflicts):
// g(r) = (r>>1)&3; LDS[r][p] holds global slot p ^ g(r) via pre-swizzled GLOBAL
// source; read at slot hi ^ ((lo>>1)&3).
// mode 0: fused q/k row-normalize (+ logit_scale*log2e on q) and scatter into
//         q/k/v head buffers (N,H,L,D) fp16.  mode 1: fp32 out (M x 768).
__global__ __launch_bounds__(256, 4) void gemm_kernel(
    const u16* __restrict__ A, const u16* __restrict__ B, const float* __restrict__ bias,
    int mode, u16* __restrict__ qh, u16* __restrict__ kh, u16* __restrict__ vh,
    float* __restrict__ outp, const float* __restrict__ lsb)
{
  __shared__ u16 lA[3][128*32];   // [buf][row(128)][slot(4) of 16B], swizzled slots
  __shared__ u16 lB[3][128*32];
  const int tid = threadIdx.x;
  const int lane = tid & 63;
  const int w = tid >> 6, wr = w >> 1, wc = w & 1;
  const int lo = lane & 15, hi = lane >> 4;

  const int bx = blockIdx.x, by = blockIdx.y;

  f32x4 zero = {0.f,0.f,0.f,0.f};
  f32x4 acc[4][4];
#pragma unroll
  for (int a=0;a<4;a++)
#pragma unroll
    for (int b=0;b<4;b++) acc[a][b] = zero;
  const u16* Ag = A + (size_t)bx*128*768;
  const u16* Bg = B + (size_t)by*128*768;
  const int sr = tid >> 2;                                   // rows sr, sr+64
  const int scol = (((tid & 3) ^ ((sr >> 1) & 3)) * 8);      // pre-swizzled 16B slot
  const int sl = (hi ^ ((lo >> 1) & 3)) * 8;                 // swizzled read slot

#define STAGE(buf, kt) do { \
    __builtin_amdgcn_global_load_lds((gas_u16*)(Ag + (size_t)sr*768 + (kt) + scol),      (las_u16*)(&lA[buf][tid*8]),        16, 0, 0); \
    __builtin_amdgcn_global_load_lds((gas_u16*)(Ag + (size_t)(sr+64)*768 + (kt) + scol), (las_u16*)(&lA[buf][2048 + tid*8]), 16, 0, 0); \
    __builtin_amdgcn_global_load_lds((gas_u16*)(Bg + (size_t)sr*768 + (kt) + scol),      (las_u16*)(&lB[buf][tid*8]),        16, 0, 0); \
    __builtin_amdgcn_global_load_lds((gas_u16*)(Bg + (size_t)(sr+64)*768 + (kt) + scol), (las_u16*)(&lB[buf][2048 + tid*8]), 16, 0, 0); \
  } while(0)

  STAGE(0, 0);
  STAGE(1, 32);
#pragma unroll
  for (int t = 0; t < 24; ++t) {
    const int cur = t % 3;
    if (t < 22) {
      STAGE((t+2)%3, (t+2)*32);                        // depth-2: issue tile t+2
      asm volatile("s_waitcnt vmcnt(8)" ::: "memory"); // tile t landed; t+1,t+2 fly
    } else if (t == 22) {
      asm volatile("s_waitcnt vmcnt(4)" ::: "memory"); // tile 22 landed; 23 flies
    } else {
      asm volatile("s_waitcnt vmcnt(0)" ::: "memory");
    }
    __builtin_amdgcn_sched_barrier(0);
    __builtin_amdgcn_s_barrier();                      // no implicit drain
    h8 af[4], bfr[4];
#pragma unroll
    for (int mf=0; mf<4; mf++) af[mf]  = *(const h8*)(&lA[cur][(wr*64 + mf*16 + lo)*32 + sl]);
#pragma unroll
    for (int nf=0; nf<4; nf++) bfr[nf] = *(const h8*)(&lB[cur][(wc*64 + nf*16 + lo)*32 + sl]);
#pragma unroll
    for (int mf=0; mf<4; mf++)
#pragma unroll
      for (int nf=0; nf<4; nf++)
        acc[mf][nf] = MFMA32(af[mf], bfr[nf], acc[mf][nf]);
    asm volatile("s_waitcnt lgkmcnt(0)" ::: "memory"); // my reads of cur retired
    __builtin_amdgcn_sched_barrier(0);
    __builtin_amdgcn_s_barrier();                      // now cur may be restaged
  }
#undef STAGE

  const int r0 = bx*128 + wr*64;
  const int j0 = by*128 + wc*64;
  if (mode == 0) {
    const int p = (j0 >= 1536) ? 2 : ((j0 >= 768) ? 1 : 0);
    const int c0 = j0 - p*768;
    const int hh = c0 >> 6;
    u16* dst = (p==0) ? qh : ((p==1) ? kh : vh);
    float bi[4];
#pragma unroll
    for (int nf=0;nf<4;nf++) bi[nf] = bias[j0 + nf*16 + lo];
    float qsc = 1.0f;
    if (p == 0) qsc = __expf(fminf(lsb[hh], 4.6051701859880913680f)) * 1.4426950408889634f;
    const bool dnorm = (p != 2);
#pragma unroll
    for (int mf=0; mf<4; mf++)
#pragma unroll
      for (int i=0;i<4;i++) {
        int r = r0 + mf*16 + 4*hi + i;
        int n = r & 7, l = r >> 3;
        float v[4]; float ss = 0.f;
#pragma unroll
        for (int nf=0;nf<4;nf++){ v[nf] = acc[mf][nf][i] + bi[nf]; ss += v[nf]*v[nf]; }
        float sc = 1.0f;
        if (dnorm) {
          ss += __shfl_xor(ss, 1);
          ss += __shfl_xor(ss, 2);
          ss += __shfl_xor(ss, 4);
          ss += __shfl_xor(ss, 8);
          sc = qsc / fmaxf(sqrtf(ss), 1e-12f);
        }
        size_t base = (((size_t)n*12 + hh)*1024 + l)*64;
#pragma unroll
        for (int nf=0;nf<4;nf++)
          dst[base + nf*16 + lo] = f2h(v[nf]*sc);
      }
  } else {
#pragma unroll
    for (int nf=0; nf<4; nf++) {
      int j = j0 + nf*16 + lo;
      float bi = bias[j];
#pragma unroll
      for (int mf=0; mf<4; mf++)
#pragma unroll
        for (int i=0;i<4;i++) {
          int r = r0 + mf*16 + 4*hi + i;
          outp[(size_t)r*768 + j] = acc[mf][nf][i] + bi;
        }
    }
  }
}

// ---------------- V transpose: (N,H,L,D) -> (N,H,D,L) ----------------
__global__ __launch_bounds__(256) void transpose_kernel(const u16* __restrict__ vh, u16* __restrict__ vt){
  __shared__ u16 tile[64*72];   // [l(64)][d] padded stride 72
  const int nh = blockIdx.y, lt = blockIdx.x, tid = threadIdx.x;
  const int r = tid >> 2, c0 = (tid & 3) * 16;
  const u16* src = vh + (size_t)nh*65536 + (size_t)(lt*64 + r)*64 + c0;
  u32x4 a = *(const u32x4*)src, b = *(const u32x4*)(src + 8);
  *(u32x4*)(tile + r*72 + c0)     = a;
  *(u32x4*)(tile + r*72 + c0 + 8) = b;
  __syncthreads();
  u16x8 o0, o1;
#pragma unroll
  for (int s=0;s<8;s++){ o0[s] = tile[(c0+s)*72 + r]; o1[s] = tile[(c0+8+s)*72 + r]; }
  u16* dst = vt + (size_t)nh*65536 + (size_t)r*1024 + lt*64 + c0;
  *(u16x8*)dst       = o0;
  *(u16x8*)(dst + 8) = o1;
}

// ---------------- flash attention (cosine-bounded: no running max needed) ----------------
// grid (16 q-tiles, 96 n*h) -> 1536 blocks = 6/CU; LDS 16KB single-buffer + VGPR<=85
// -> 24 waves/CU. XOR-swizzled [64][64] tiles; raw s_barrier + lgkmcnt(0) keeps the
// next-tile global prefetch in flight across the barrier (T4). See round-8 notes.
__global__ __launch_bounds__(256, 6) void flash_kernel(
    const u16* __restrict__ qh, const u16* __restrict__ kh, const u16* __restrict__ vt,
    u16* __restrict__ obuf, const float* __restrict__ hsv, const float* __restrict__ lsp)
{
  __shared__ u16 lK[64*64];    // [k][d] swizzled 16B slots
  __shared__ u16 lVT[64*64];   // [d][k] permuted+swizzled 8B chunks
  // XCD-locality remap: 12 heads x 16 q-tiles per XCD (3MB K+V resident in L2)
  const int lin = blockIdx.y*16 + blockIdx.x;
  const int xcd = lin & 7, g = lin >> 3;
  const int nh = xcd + 8*(g >> 4);
  const int qt = g & 15;
  const int h = nh % 12, n = nh / 12;
  const u16* Qp = qh + (size_t)nh*65536;
  const u16* Kp = kh + (size_t)nh*65536;
  const u16* Vp = vt + (size_t)nh*65536;
  const int tid = threadIdx.x, lane = tid & 63, w = tid >> 6;
  const int lo = lane & 15, hi = lane >> 4;
  const int e = lo & 7;

  // Q fragments: lane holds Q[q=lo][d = hi*8 + j] (+32)
  h8 qa0, qa1;
  {
    const u16* qrow = Qp + (size_t)(qt*64 + w*16 + lo)*64 + hi*8;
    qa0 = *(const h8*)qrow;
    qa1 = *(const h8*)(qrow + 32);
  }
  const f32x4 zero = {0.f,0.f,0.f,0.f};
  f32x4 oA[4] = {zero,zero,zero,zero};   // O^T[d=db*16+4hi+i][q=lo]
  f32x4 lA4 = zero;                      // row sums via ones-MFMA
  const h4 ones = {(f16)1.f,(f16)1.f,(f16)1.f,(f16)1.f};

  // fp16-overflow guard (0 for these inputs; uniform branch if ever nonzero)
  float OFF;
  {
    float b = __expf(fminf(lsp[h], 4.6051701859880913680f)) * 1.4426950408889634f;
    OFF = fmaxf(b - 15.5f, 0.f);
  }

  const int sr = tid >> 2;          // stage row (k for lK, d for lVT), 0..63
  const int c4 = tid & 3;           // stage 16B-column group
  const int sx1 = sr & 7;           // K slot16 XOR
  const int sx2 = (sr & 7) << 1;    // VT chunk8 XOR (even)

  u32x4 ka, kb, va, vb;
  ka = *(const u32x4*)(Kp + (size_t)sr*64 + c4*16);
  kb = *(const u32x4*)(Kp + (size_t)sr*64 + c4*16 + 8);
  va = *(const u32x4*)(Vp + (size_t)sr*1024 + c4*16);
  vb = *(const u32x4*)(Vp + (size_t)sr*1024 + c4*16 + 8);

  for (int t = 0; t < 16; ++t) {
    // ---- stage regs -> LDS (swizzled) ----
    {
      u16* kr = lK + sr*64;
      *(u32x4*)(kr + (((2*c4)   ^ sx1) << 3)) = ka;
      *(u32x4*)(kr + (((2*c4+1) ^ sx1) << 3)) = kb;
      u16* vr = lVT + sr*64;
      *(u32x2*)(vr + (((( 0|c4) ^ sx2) << 2))) = (u32x2){va[0], va[1]};
      *(u32x2*)(vr + (((( 4|c4) ^ sx2) << 2))) = (u32x2){va[2], va[3]};
      *(u32x2*)(vr + (((( 8|c4) ^ sx2) << 2))) = (u32x2){vb[0], vb[1]};
      *(u32x2*)(vr + ((((12|c4) ^ sx2) << 2))) = (u32x2){vb[2], vb[3]};
    }
    asm volatile("s_waitcnt lgkmcnt(0)" ::: "memory");
    __builtin_amdgcn_sched_barrier(0);
    __builtin_amdgcn_s_barrier();                // tile visible to all waves
    if (t < 15) {  // prefetch next tile into regs; stays in flight across barrier
      ka = *(const u32x4*)(Kp + (size_t)(t+1)*4096 + (size_t)sr*64 + c4*16);
      kb = *(const u32x4*)(Kp + (size_t)(t+1)*4096 + (size_t)sr*64 + c4*16 + 8);
      va = *(const u32x4*)(Vp + (size_t)sr*1024 + (t+1)*64 + c4*16);
      vb = *(const u32x4*)(Vp + (size_t)sr*1024 + (t+1)*64 + c4*16 + 8);
    }
    // ---- S^T = K . Q^T ----
    f32x4 sa[4];
#pragma unroll
    for (int kf=0; kf<4; kf++) {
      const u16* krow = lK + (kf*16 + lo)*64;
      h8 k0 = *(const h8*)(krow + (((hi  ) ^ e) << 3));
      h8 k1 = *(const h8*)(krow + (((hi+4) ^ e) << 3));
      sa[kf] = MFMA32(k1, qa1, MFMA32(k0, qa0, zero));
    }
    if (OFF != 0.f) {
#pragma unroll
      for (int kf=0;kf<4;kf++)
#pragma unroll
        for (int i=0;i<4;i++) sa[kf][i] -= OFF;
    }
    // ---- p = exp2(s), packed into mfma16 B-operand layout ----
    h4 pa[4];
#pragma unroll
    for (int kf=0;kf<4;kf++) {
      h2 a01 = pkrtz(fast_exp2(sa[kf][0]), fast_exp2(sa[kf][1]));
      h2 a23 = pkrtz(fast_exp2(sa[kf][2]), fast_exp2(sa[kf][3]));
      pa[kf] = __builtin_shufflevector(a01, a23, 0, 1, 2, 3);
    }
    // ---- row sums on the matrix pipe ----
#pragma unroll
    for (int kf=0;kf<4;kf++) lA4 = MFMA16(ones, pa[kf], lA4);
    // ---- PV: O^T += VT-frag x P-frag (2 b128 V-reads per db) ----
#pragma unroll
    for (int db=0; db<4; db++) {
      const u16* vrow = lVT + (db*16 + lo)*64;
      h8 v01 = *(const h8*)(vrow + ((((2*hi  ) ^ e) << 3)));
      h8 v23 = *(const h8*)(vrow + ((((2*hi+1) ^ e) << 3)));
      oA[db] = MFMA16(__builtin_shufflevector(v01, v01, 0,1,2,3), pa[0], oA[db]);
      oA[db] = MFMA16(__builtin_shufflevector(v01, v01, 4,5,6,7), pa[1], oA[db]);
      oA[db] = MFMA16(__builtin_shufflevector(v23, v23, 0,1,2,3), pa[2], oA[db]);
      oA[db] = MFMA16(__builtin_shufflevector(v23, v23, 4,5,6,7), pa[3], oA[db]);
    }
    asm volatile("s_waitcnt lgkmcnt(0)" ::: "memory"); // my reads retired
    __builtin_amdgcn_sched_barrier(0);
    __builtin_amdgcn_s_barrier();                      // safe to restage
  }
  // epilogue: O[q][d] = O^T / l * head_scale, store fp16 into (L,N,C)
  float inv = hsv[h] / lA4[0];
  int l = qt*64 + w*16 + lo;
  u16* dst = obuf + ((size_t)l*8 + n)*768 + h*64;
#pragma unroll
  for (int db=0; db<4; db++) {
    u16x4 pk;
#pragma unroll
    for (int i=0;i<4;i++) pk[i] = f2h(oA[db][i] * inv);
    *(u16x4*)(dst + db*16 + hi*4) = pk;
  }
}

extern "C" void kernel_launch(void* const* d_in, const int* in_sizes, int n_in,
                              void* d_out, int out_size, void* d_ws, size_t ws_size,
                              hipStream_t stream)
{
  (void)in_sizes; (void)n_in; (void)out_size; (void)ws_size;
  const float* x  = (const float*)d_in[0];
  const float* w1 = (const float*)d_in[1];
  const float* b1 = (const float*)d_in[2];
  const float* ls = (const float*)d_in[3];
  const float* hs = (const float*)d_in[4];
  const float* w2 = (const float*)d_in[5];
  const float* b2 = (const float*)d_in[6];
  float* out = (float*)d_out;

  u16* x_bf  = (u16*)d_ws;            // 8192 x 768  (reused as ob after GEMM1)
  u16* w1_bf = x_bf  + 6291456;       // 2304 x 768
  u16* w2_bf = w1_bf + 1769472;       // 768 x 768
  u16* qh    = w2_bf + 589824;        // (N,H,L,D) normalized (+ls*log2e on q)
  u16* kh    = qh    + 6291456;
  u16* vh    = kh    + 6291456;
  u16* vt    = vh    + 6291456;       // (N,H,D,L)
  u16* ob    = x_bf;                  // (L,N,C) fp16, aliases x_bf

  cvt3_kernel<<<8448, 256, 0, stream>>>(x, x_bf, w1, w1_bf, w2, w2_bf);
  gemm_kernel<<<dim3(64,18), 256, 0, stream>>>(x_bf, w1_bf, b1, 0, qh, kh, vh, nullptr, ls);
  transpose_kernel<<<dim3(16,96), 256, 0, stream>>>(vh, vt);
  flash_kernel<<<dim3(16,96), 256, 0, stream>>>(qh, kh, vt, ob, hs, ls);
  gemm_kernel<<<dim3(64,6), 256, 0, stream>>>(ob, w2_bf, b2, 1, nullptr, nullptr, nullptr, out, ls);
}

// Round 12
// 123.730 us; speedup vs baseline: 1.0790x; 1.0790x over previous
//
#include <hip/hip_runtime.h>
#include <stdint.h>
#include <math.h>

typedef unsigned short u16;
typedef _Float16 f16;
typedef __attribute__((ext_vector_type(4))) float f32x4;
typedef __attribute__((ext_vector_type(8))) f16 h8;
typedef __attribute__((ext_vector_type(4))) f16 h4;
typedef __attribute__((ext_vector_type(2))) f16 h2;
typedef __attribute__((ext_vector_type(2))) __fp16 fp16x2;
typedef __attribute__((ext_vector_type(2))) unsigned int u32x2;
typedef __attribute__((ext_vector_type(4))) unsigned int u32x4;
typedef __attribute__((ext_vector_type(4))) unsigned short u16x4;
typedef __attribute__((ext_vector_type(8))) unsigned short u16x8;

typedef const __attribute__((address_space(1))) u16 gas_u16;
typedef __attribute__((address_space(3))) u16 las_u16;

#define MFMA32(a,b,c) __builtin_amdgcn_mfma_f32_16x16x32_f16((a),(b),(c),0,0,0)
#define MFMA16(a,b,c) __builtin_amdgcn_mfma_f32_16x16x16f16((a),(b),(c),0,0,0)

__device__ __forceinline__ float h2f(u16 h){ f16 x; __builtin_memcpy(&x,&h,2); return (float)x; }
__device__ __forceinline__ u16 f2h(float f){ f16 x = (f16)f; u16 u; __builtin_memcpy(&u,&x,2); return u; }

__device__ __forceinline__ float fast_exp2(float x){
#if __has_builtin(__builtin_amdgcn_exp2f)
  return __builtin_amdgcn_exp2f(x);
#else
  return exp2f(x);
#endif
}

// pack two f32 -> two f16 in one v_cvt_pkrtz; bit-cast to _Float16 vector type
__device__ __forceinline__ h2 pkrtz(float a, float b){
  fp16x2 t = __builtin_amdgcn_cvt_pkrtz(a, b);
  h2 r; __builtin_memcpy(&r, &t, 4);
  return r;
}

// ---------------- fused fp32 -> fp16 convert (x, w1, w2 in one launch) ----------------
#define NA4 1572864
#define NB4 442368
#define NC4 147456
__global__ __launch_bounds__(256) void cvt3_kernel(
    const float* __restrict__ a, u16* __restrict__ da,
    const float* __restrict__ b, u16* __restrict__ db,
    const float* __restrict__ c, u16* __restrict__ dc)
{
  int i = blockIdx.x*256 + threadIdx.x;
  const float* s; u16* d; int off;
  if (i < NA4)            { s = a; d = da; off = i; }
  else if (i < NA4+NB4)   { s = b; d = db; off = i - NA4; }
  else if (i < NA4+NB4+NC4){ s = c; d = dc; off = i - NA4 - NB4; }
  else return;
  f32x4 v = ((const f32x4*)s)[off];
  u16x4 o;
  o[0]=f2h(v[0]); o[1]=f2h(v[1]); o[2]=f2h(v[2]); o[3]=f2h(v[3]);
  ((u16x4*)d)[off] = o;
}

// ---------------- fp16 GEMM, C = A(M x 768) * B(N x 768)^T + bias ----------------
// R8-proven main loop: T4 counted-vmcnt dbuf at BK=64 (12 K-steps, vmcnt(8),
// raw s_barrier; 52.5us — best of 4 structures tested R8-R11; the 128^2-tile
// 2-barrier structure plateaus at ~52-54us regardless of BK/depth/occupancy).
// NEW: transpose_kernel FUSED into the mode-0 V epilogue. p is block-uniform
// (by>=12 -> whole block is V); after the K-loop the 64KB staging LDS is dead,
// so acc(+bias,fp16) goes into an XOR-swizzled LDS tile T[d(64)][r(128)]
// (chunk c -> c ^ ((d&7)<<2): write u16x4 2-way, read 2-way), barrier, then each
// thread gathers 8 l-consecutive elems and writes 16B chunks directly to vt
// (N,H,D,L). Saves 25MB HBM (vh write + vh re-read) + one kernel launch.
// mode 0: q/k row-normalize (+ logit_scale*log2e on q) scatter + V transpose.
// mode 1: fp32 out (M x 768).
__global__ __launch_bounds__(256) void gemm_kernel(
    const u16* __restrict__ A, const u16* __restrict__ B, const float* __restrict__ bias,
    int mode, u16* __restrict__ qh, u16* __restrict__ kh, u16* __restrict__ vtp,
    float* __restrict__ outp, const float* __restrict__ lsb)
{
  __shared__ u16 lA[2][128*64];   // [buf][row(128)][slot(8) of 16B], swizzled slots
  __shared__ u16 lB[2][128*64];
  const int tid = threadIdx.x;
  const int lane = tid & 63;
  const int w = tid >> 6, wr = w >> 1, wc = w & 1;
  const int lo = lane & 15, hi = lane >> 4;

  const int bx = blockIdx.x, by = blockIdx.y;

  f32x4 zero = {0.f,0.f,0.f,0.f};
  f32x4 acc[4][4];
#pragma unroll
  for (int a=0;a<4;a++)
#pragma unroll
    for (int b=0;b<4;b++) acc[a][b] = zero;
  const u16* Ag = A + (size_t)bx*128*768;
  const u16* Bg = B + (size_t)by*128*768;
  const int srow = tid >> 3;                         // 0..31 (+j*32)
  const int scol = (((tid & 7) ^ (srow & 7)) * 8);   // pre-swizzled source 16B-slot

#define STAGE(buf, kt) do { \
    _Pragma("unroll") \
    for (int j=0;j<4;j++) { \
      __builtin_amdgcn_global_load_lds((gas_u16*)(Ag + (size_t)(j*32+srow)*768 + (kt) + scol), (las_u16*)(&lA[buf][j*2048 + tid*8]), 16, 0, 0); \
      __builtin_amdgcn_global_load_lds((gas_u16*)(Bg + (size_t)(j*32+srow)*768 + (kt) + scol), (las_u16*)(&lB[buf][j*2048 + tid*8]), 16, 0, 0); \
    } \
  } while(0)

  STAGE(0, 0);
#pragma unroll
  for (int t = 0; t < 12; ++t) {
    const int cur = t & 1;
    if (t < 11) {
      STAGE(cur^1, (t+1)*64);                         // next tile: 8 loads in flight
      asm volatile("s_waitcnt vmcnt(8)" ::: "memory"); // current tile landed
    } else {
      asm volatile("s_waitcnt vmcnt(0)" ::: "memory");
    }
    __builtin_amdgcn_sched_barrier(0);
    __builtin_amdgcn_s_barrier();                     // no implicit drain
#pragma unroll
    for (int kk=0;kk<2;kk++) {
      h8 af[4], bfr[4];
#pragma unroll
      for (int mf=0; mf<4; mf++) {
        int r = wr*64 + mf*16 + lo;
        af[mf]  = *(const h8*)(&lA[cur][r*64 + (((hi + 4*kk) ^ (lo & 7)) * 8)]);
      }
#pragma unroll
      for (int nf=0; nf<4; nf++) {
        int r = wc*64 + nf*16 + lo;
        bfr[nf] = *(const h8*)(&lB[cur][r*64 + (((hi + 4*kk) ^ (lo & 7)) * 8)]);
      }
#pragma unroll
      for (int mf=0; mf<4; mf++)
#pragma unroll
        for (int nf=0; nf<4; nf++)
          acc[mf][nf] = MFMA32(af[mf], bfr[nf], acc[mf][nf]);
    }
    asm volatile("s_waitcnt lgkmcnt(0)" ::: "memory"); // my reads of cur retired
    __builtin_amdgcn_sched_barrier(0);
    __builtin_amdgcn_s_barrier();                      // now cur may be restaged
  }
#undef STAGE

  const int r0 = bx*128 + wr*64;
  const int j0 = by*128 + wc*64;
  if (mode == 0) {
    const int p = (j0 >= 1536) ? 2 : ((j0 >= 768) ? 1 : 0);
    float bi[4];
#pragma unroll
    for (int nf=0;nf<4;nf++) bi[nf] = bias[j0 + nf*16 + lo];
    if (p == 2) {
      // ---- V: transposed store via dead staging LDS ----
      // T[d(64)][r(128)], 4-elem chunk c stored at c ^ ((d&7)<<2).
      u16* Tt = (wc == 0) ? (u16*)lA : (u16*)lB;
      const int cbase = wr*16;                // chunk base for this wave's rows
#pragma unroll
      for (int mf=0; mf<4; mf++)
#pragma unroll
        for (int nf=0; nf<4; nf++) {
          int d = nf*16 + lo;
          int c = cbase + mf*4 + hi;          // r-chunk (r = c*4 + i)
          u16x4 pk;
#pragma unroll
          for (int i=0;i<4;i++) pk[i] = f2h(acc[mf][nf][i] + bi[nf]);
          *(u16x4*)(Tt + d*128 + ((c ^ ((d & 7) << 2)) << 2)) = pk;
        }
      __syncthreads();
      // gather 8 l-consecutive elems per task, write 16B to vt
      const int hh0 = 2*by - 24;              // head for wc=0; +1 for wc=1
#pragma unroll
      for (int kq=0; kq<8; kq++) {
        int idx = tid + kq*256;               // [wcc][lh][d][nn], nn fastest
        int nn  = idx & 7;
        int d   = (idx >> 3) & 63;
        int lh  = (idx >> 9) & 1;
        int wcc = idx >> 10;
        const u16* Ts = (wcc == 0) ? (const u16*)lA : (const u16*)lB;
        u16x8 v8;
#pragma unroll
        for (int ll=0; ll<8; ll++) {
          int rl = (lh*8 + ll)*8 + nn;        // r_local = l_local*8 + n
          int c  = rl >> 2;
          v8[ll] = Ts[d*128 + ((c ^ ((d & 7) << 2)) << 2) + (rl & 3)];
        }
        size_t off = (((size_t)nn*12 + hh0 + wcc)*64 + d)*1024 + (size_t)bx*16 + lh*8;
        *(u16x8*)(vtp + off) = v8;
      }
    } else {
      // ---- q/k: fused row-normalize + scatter ----
      const int c0 = j0 - p*768;
      const int hh = c0 >> 6;
      u16* dst = (p==0) ? qh : kh;
      float qsc = 1.0f;
      if (p == 0) qsc = __expf(fminf(lsb[hh], 4.6051701859880913680f)) * 1.4426950408889634f;
#pragma unroll
      for (int mf=0; mf<4; mf++)
#pragma unroll
        for (int i=0;i<4;i++) {
          int r = r0 + mf*16 + 4*hi + i;
          int n = r & 7, l = r >> 3;
          float v[4]; float ss = 0.f;
#pragma unroll
          for (int nf=0;nf<4;nf++){ v[nf] = acc[mf][nf][i] + bi[nf]; ss += v[nf]*v[nf]; }
          ss += __shfl_xor(ss, 1);
          ss += __shfl_xor(ss, 2);
          ss += __shfl_xor(ss, 4);
          ss += __shfl_xor(ss, 8);
          float sc = qsc / fmaxf(sqrtf(ss), 1e-12f);
          size_t base = (((size_t)n*12 + hh)*1024 + l)*64;
#pragma unroll
          for (int nf=0;nf<4;nf++)
            dst[base + nf*16 + lo] = f2h(v[nf]*sc);
        }
    }
  } else {
#pragma unroll
    for (int nf=0; nf<4; nf++) {
      int j = j0 + nf*16 + lo;
      float bi = bias[j];
#pragma unroll
      for (int mf=0; mf<4; mf++)
#pragma unroll
        for (int i=0;i<4;i++) {
          int r = r0 + mf*16 + 4*hi + i;
          outp[(size_t)r*768 + j] = acc[mf][nf][i] + bi;
        }
    }
  }
}

// ---------------- flash attention (cosine-bounded: no running max needed) ----------------
// grid (16 q-tiles, 96 n*h) -> 1536 blocks = 6/CU; LDS 16KB single-buffer + VGPR<=85
// -> 24 waves/CU. XOR-swizzled [64][64] tiles; raw s_barrier + lgkmcnt(0) keeps the
// next-tile global prefetch in flight across the barrier (T4). See round-8 notes.
__global__ __launch_bounds__(256, 6) void flash_kernel(
    const u16* __restrict__ qh, const u16* __restrict__ kh, const u16* __restrict__ vt,
    u16* __restrict__ obuf, const float* __restrict__ hsv, const float* __restrict__ lsp)
{
  __shared__ u16 lK[64*64];    // [k][d] swizzled 16B slots
  __shared__ u16 lVT[64*64];   // [d][k] permuted+swizzled 8B chunks
  // XCD-locality remap: 12 heads x 16 q-tiles per XCD (3MB K+V resident in L2)
  const int lin = blockIdx.y*16 + blockIdx.x;
  const int xcd = lin & 7, g = lin >> 3;
  const int nh = xcd + 8*(g >> 4);
  const int qt = g & 15;
  const int h = nh % 12, n = nh / 12;
  const u16* Qp = qh + (size_t)nh*65536;
  const u16* Kp = kh + (size_t)nh*65536;
  const u16* Vp = vt + (size_t)nh*65536;
  const int tid = threadIdx.x, lane = tid & 63, w = tid >> 6;
  const int lo = lane & 15, hi = lane >> 4;
  const int e = lo & 7;

  // Q fragments: lane holds Q[q=lo][d = hi*8 + j] (+32)
  h8 qa0, qa1;
  {
    const u16* qrow = Qp + (size_t)(qt*64 + w*16 + lo)*64 + hi*8;
    qa0 = *(const h8*)qrow;
    qa1 = *(const h8*)(qrow + 32);
  }
  const f32x4 zero = {0.f,0.f,0.f,0.f};
  f32x4 oA[4] = {zero,zero,zero,zero};   // O^T[d=db*16+4hi+i][q=lo]
  f32x4 lA4 = zero;                      // row sums via ones-MFMA
  const h4 ones = {(f16)1.f,(f16)1.f,(f16)1.f,(f16)1.f};

  // fp16-overflow guard (0 for these inputs; uniform branch if ever nonzero)
  float OFF;
  {
    float b = __expf(fminf(lsp[h], 4.6051701859880913680f)) * 1.4426950408889634f;
    OFF = fmaxf(b - 15.5f, 0.f);
  }

  const int sr = tid >> 2;          // stage row (k for lK, d for lVT), 0..63
  const int c4 = tid & 3;           // stage 16B-column group
  const int sx1 = sr & 7;           // K slot16 XOR
  const int sx2 = (sr & 7) << 1;    // VT chunk8 XOR (even)

  u32x4 ka, kb, va, vb;
  ka = *(const u32x4*)(Kp + (size_t)sr*64 + c4*16);
  kb = *(const u32x4*)(Kp + (size_t)sr*64 + c4*16 + 8);
  va = *(const u32x4*)(Vp + (size_t)sr*1024 + c4*16);
  vb = *(const u32x4*)(Vp + (size_t)sr*1024 + c4*16 + 8);

  for (int t = 0; t < 16; ++t) {
    // ---- stage regs -> LDS (swizzled) ----
    {
      u16* kr = lK + sr*64;
      *(u32x4*)(kr + (((2*c4)   ^ sx1) << 3)) = ka;
      *(u32x4*)(kr + (((2*c4+1) ^ sx1) << 3)) = kb;
      u16* vr = lVT + sr*64;
      *(u32x2*)(vr + (((( 0|c4) ^ sx2) << 2))) = (u32x2){va[0], va[1]};
      *(u32x2*)(vr + (((( 4|c4) ^ sx2) << 2))) = (u32x2){va[2], va[3]};
      *(u32x2*)(vr + (((( 8|c4) ^ sx2) << 2))) = (u32x2){vb[0], vb[1]};
      *(u32x2*)(vr + ((((12|c4) ^ sx2) << 2))) = (u32x2){vb[2], vb[3]};
    }
    asm volatile("s_waitcnt lgkmcnt(0)" ::: "memory");
    __builtin_amdgcn_sched_barrier(0);
    __builtin_amdgcn_s_barrier();                // tile visible to all waves
    if (t < 15) {  // prefetch next tile into regs; stays in flight across barrier
      ka = *(const u32x4*)(Kp + (size_t)(t+1)*4096 + (size_t)sr*64 + c4*16);
      kb = *(const u32x4*)(Kp + (size_t)(t+1)*4096 + (size_t)sr*64 + c4*16 + 8);
      va = *(const u32x4*)(Vp + (size_t)sr*1024 + (t+1)*64 + c4*16);
      vb = *(const u32x4*)(Vp + (size_t)sr*1024 + (t+1)*64 + c4*16 + 8);
    }
    // ---- S^T = K . Q^T ----
    f32x4 sa[4];
#pragma unroll
    for (int kf=0; kf<4; kf++) {
      const u16* krow = lK + (kf*16 + lo)*64;
      h8 k0 = *(const h8*)(krow + (((hi  ) ^ e) << 3));
      h8 k1 = *(const h8*)(krow + (((hi+4) ^ e) << 3));
      sa[kf] = MFMA32(k1, qa1, MFMA32(k0, qa0, zero));
    }
    if (OFF != 0.f) {
#pragma unroll
      for (int kf=0;kf<4;kf++)
#pragma unroll
        for (int i=0;i<4;i++) sa[kf][i] -= OFF;
    }
    // ---- p = exp2(s), packed into mfma16 B-operand layout ----
    h4 pa[4];
#pragma unroll
    for (int kf=0;kf<4;kf++) {
      h2 a01 = pkrtz(fast_exp2(sa[kf][0]), fast_exp2(sa[kf][1]));
      h2 a23 = pkrtz(fast_exp2(sa[kf][2]), fast_exp2(sa[kf][3]));
      pa[kf] = __builtin_shufflevector(a01, a23, 0, 1, 2, 3);
    }
    // ---- row sums on the matrix pipe ----
#pragma unroll
    for (int kf=0;kf<4;kf++) lA4 = MFMA16(ones, pa[kf], lA4);
    // ---- PV: O^T += VT-frag x P-frag (2 b128 V-reads per db) ----
#pragma unroll
    for (int db=0; db<4; db++) {
      const u16* vrow = lVT + (db*16 + lo)*64;
      h8 v01 = *(const h8*)(vrow + ((((2*hi  ) ^ e) << 3)));
      h8 v23 = *(const h8*)(vrow + ((((2*hi+1) ^ e) << 3)));
      oA[db] = MFMA16(__builtin_shufflevector(v01, v01, 0,1,2,3), pa[0], oA[db]);
      oA[db] = MFMA16(__builtin_shufflevector(v01, v01, 4,5,6,7), pa[1], oA[db]);
      oA[db] = MFMA16(__builtin_shufflevector(v23, v23, 0,1,2,3), pa[2], oA[db]);
      oA[db] = MFMA16(__builtin_shufflevector(v23, v23, 4,5,6,7), pa[3], oA[db]);
    }
    asm volatile("s_waitcnt lgkmcnt(0)" ::: "memory"); // my reads retired
    __builtin_amdgcn_sched_barrier(0);
    __builtin_amdgcn_s_barrier();                      // safe to restage
  }
  // epilogue: O[q][d] = O^T / l * head_scale, store fp16 into (L,N,C)
  float inv = hsv[h] / lA4[0];
  int l = qt*64 + w*16 + lo;
  u16* dst = obuf + ((size_t)l*8 + n)*768 + h*64;
#pragma unroll
  for (int db=0; db<4; db++) {
    u16x4 pk;
#pragma unroll
    for (int i=0;i<4;i++) pk[i] = f2h(oA[db][i] * inv);
    *(u16x4*)(dst + db*16 + hi*4) = pk;
  }
}

extern "C" void kernel_launch(void* const* d_in, const int* in_sizes, int n_in,
                              void* d_out, int out_size, void* d_ws, size_t ws_size,
                              hipStream_t stream)
{
  (void)in_sizes; (void)n_in; (void)out_size; (void)ws_size;
  const float* x  = (const float*)d_in[0];
  const float* w1 = (const float*)d_in[1];
  const float* b1 = (const float*)d_in[2];
  const float* ls = (const float*)d_in[3];
  const float* hs = (const float*)d_in[4];
  const float* w2 = (const float*)d_in[5];
  const float* b2 = (const float*)d_in[6];
  float* out = (float*)d_out;

  u16* x_bf  = (u16*)d_ws;            // 8192 x 768  (reused as ob after GEMM1)
  u16* w1_bf = x_bf  + 6291456;       // 2304 x 768
  u16* w2_bf = w1_bf + 1769472;       // 768 x 768
  u16* qh    = w2_bf + 589824;        // (N,H,L,D) normalized (+ls*log2e on q)
  u16* kh    = qh    + 6291456;
  u16* vt    = kh    + 6291456;       // (N,H,D,L) — written directly by gemm1
  u16* ob    = x_bf;                  // (L,N,C) fp16, aliases x_bf

  cvt3_kernel<<<8448, 256, 0, stream>>>(x, x_bf, w1, w1_bf, w2, w2_bf);
  gemm_kernel<<<dim3(64,18), 256, 0, stream>>>(x_bf, w1_bf, b1, 0, qh, kh, vt, nullptr, ls);
  flash_kernel<<<dim3(16,96), 256, 0, stream>>>(qh, kh, vt, ob, hs, ls);
  gemm_kernel<<<dim3(64,6), 256, 0, stream>>>(ob, w2_bf, b2, 1, nullptr, nullptr, nullptr, out, ls);
}

// Round 13
// 118.281 us; speedup vs baseline: 1.1287x; 1.0461x over previous
//
#include <hip/hip_runtime.h>
#include <stdint.h>
#include <math.h>

typedef unsigned short u16;
typedef _Float16 f16;
typedef __attribute__((ext_vector_type(4))) float f32x4;
typedef __attribute__((ext_vector_type(8))) f16 h8;
typedef __attribute__((ext_vector_type(4))) f16 h4;
typedef __attribute__((ext_vector_type(2))) f16 h2;
typedef __attribute__((ext_vector_type(2))) __fp16 fp16x2;
typedef __attribute__((ext_vector_type(2))) unsigned int u32x2;
typedef __attribute__((ext_vector_type(4))) unsigned int u32x4;
typedef __attribute__((ext_vector_type(4))) unsigned short u16x4;
typedef __attribute__((ext_vector_type(8))) unsigned short u16x8;

typedef const __attribute__((address_space(1))) u16 gas_u16;
typedef __attribute__((address_space(3))) u16 las_u16;

#define MFMA32(a,b,c) __builtin_amdgcn_mfma_f32_16x16x32_f16((a),(b),(c),0,0,0)
#define MFMA16(a,b,c) __builtin_amdgcn_mfma_f32_16x16x16f16((a),(b),(c),0,0,0)

__device__ __forceinline__ float h2f(u16 h){ f16 x; __builtin_memcpy(&x,&h,2); return (float)x; }
__device__ __forceinline__ u16 f2h(float f){ f16 x = (f16)f; u16 u; __builtin_memcpy(&u,&x,2); return u; }

__device__ __forceinline__ float fast_exp2(float x){
#if __has_builtin(__builtin_amdgcn_exp2f)
  return __builtin_amdgcn_exp2f(x);
#else
  return exp2f(x);
#endif
}

// pack two f32 -> two f16 in one v_cvt_pkrtz; bit-cast to _Float16 vector type
__device__ __forceinline__ h2 pkrtz(float a, float b){
  fp16x2 t = __builtin_amdgcn_cvt_pkrtz(a, b);
  h2 r; __builtin_memcpy(&r, &t, 4);
  return r;
}

// ---------------- fused fp32 -> fp16 convert (x, w1, w2 in one launch) ----------------
#define NA4 1572864
#define NB4 442368
#define NC4 147456
__global__ __launch_bounds__(256) void cvt3_kernel(
    const float* __restrict__ a, u16* __restrict__ da,
    const float* __restrict__ b, u16* __restrict__ db,
    const float* __restrict__ c, u16* __restrict__ dc)
{
  int i = blockIdx.x*256 + threadIdx.x;
  const float* s; u16* d; int off;
  if (i < NA4)            { s = a; d = da; off = i; }
  else if (i < NA4+NB4)   { s = b; d = db; off = i - NA4; }
  else if (i < NA4+NB4+NC4){ s = c; d = dc; off = i - NA4 - NB4; }
  else return;
  f32x4 v = ((const f32x4*)s)[off];
  u16x4 o;
  o[0]=f2h(v[0]); o[1]=f2h(v[1]); o[2]=f2h(v[2]); o[3]=f2h(v[3]);
  ((u16x4*)d)[off] = o;
}

// ---------------- fp16 GEMM, C = A(M x 768) * B(N x 768)^T + bias ----------------
// R8-proven main loop: T4 counted-vmcnt dbuf at BK=64 (12 K-steps, vmcnt(8),
// raw s_barrier). transpose fused into the mode-0 V epilogue (round 12, kept).
// mode 0: q/k row-normalize (+ logit_scale*log2e on q) scatter + V transpose.
// mode 1: fp32 out (M x 768).
__global__ __launch_bounds__(256) void gemm_kernel(
    const u16* __restrict__ A, const u16* __restrict__ B, const float* __restrict__ bias,
    int mode, u16* __restrict__ qh, u16* __restrict__ kh, u16* __restrict__ vtp,
    float* __restrict__ outp, const float* __restrict__ lsb)
{
  __shared__ u16 lA[2][128*64];   // [buf][row(128)][slot(8) of 16B], swizzled slots
  __shared__ u16 lB[2][128*64];
  const int tid = threadIdx.x;
  const int lane = tid & 63;
  const int w = tid >> 6, wr = w >> 1, wc = w & 1;
  const int lo = lane & 15, hi = lane >> 4;

  const int bx = blockIdx.x, by = blockIdx.y;

  f32x4 zero = {0.f,0.f,0.f,0.f};
  f32x4 acc[4][4];
#pragma unroll
  for (int a=0;a<4;a++)
#pragma unroll
    for (int b=0;b<4;b++) acc[a][b] = zero;
  const u16* Ag = A + (size_t)bx*128*768;
  const u16* Bg = B + (size_t)by*128*768;
  const int srow = tid >> 3;                         // 0..31 (+j*32)
  const int scol = (((tid & 7) ^ (srow & 7)) * 8);   // pre-swizzled source 16B-slot

#define STAGE(buf, kt) do { \
    _Pragma("unroll") \
    for (int j=0;j<4;j++) { \
      __builtin_amdgcn_global_load_lds((gas_u16*)(Ag + (size_t)(j*32+srow)*768 + (kt) + scol), (las_u16*)(&lA[buf][j*2048 + tid*8]), 16, 0, 0); \
      __builtin_amdgcn_global_load_lds((gas_u16*)(Bg + (size_t)(j*32+srow)*768 + (kt) + scol), (las_u16*)(&lB[buf][j*2048 + tid*8]), 16, 0, 0); \
    } \
  } while(0)

  STAGE(0, 0);
#pragma unroll
  for (int t = 0; t < 12; ++t) {
    const int cur = t & 1;
    if (t < 11) {
      STAGE(cur^1, (t+1)*64);                         // next tile: 8 loads in flight
      asm volatile("s_waitcnt vmcnt(8)" ::: "memory"); // current tile landed
    } else {
      asm volatile("s_waitcnt vmcnt(0)" ::: "memory");
    }
    __builtin_amdgcn_sched_barrier(0);
    __builtin_amdgcn_s_barrier();                     // no implicit drain
#pragma unroll
    for (int kk=0;kk<2;kk++) {
      h8 af[4], bfr[4];
#pragma unroll
      for (int mf=0; mf<4; mf++) {
        int r = wr*64 + mf*16 + lo;
        af[mf]  = *(const h8*)(&lA[cur][r*64 + (((hi + 4*kk) ^ (lo & 7)) * 8)]);
      }
#pragma unroll
      for (int nf=0; nf<4; nf++) {
        int r = wc*64 + nf*16 + lo;
        bfr[nf] = *(const h8*)(&lB[cur][r*64 + (((hi + 4*kk) ^ (lo & 7)) * 8)]);
      }
#pragma unroll
      for (int mf=0; mf<4; mf++)
#pragma unroll
        for (int nf=0; nf<4; nf++)
          acc[mf][nf] = MFMA32(af[mf], bfr[nf], acc[mf][nf]);
    }
    asm volatile("s_waitcnt lgkmcnt(0)" ::: "memory"); // my reads of cur retired
    __builtin_amdgcn_sched_barrier(0);
    __builtin_amdgcn_s_barrier();                      // now cur may be restaged
  }
#undef STAGE

  const int r0 = bx*128 + wr*64;
  const int j0 = by*128 + wc*64;
  if (mode == 0) {
    const int p = (j0 >= 1536) ? 2 : ((j0 >= 768) ? 1 : 0);
    float bi[4];
#pragma unroll
    for (int nf=0;nf<4;nf++) bi[nf] = bias[j0 + nf*16 + lo];
    if (p == 2) {
      // ---- V: transposed store via dead staging LDS ----
      // T[d(64)][r(128)], 4-elem chunk c stored at c ^ ((d&7)<<2).
      u16* Tt = (wc == 0) ? (u16*)lA : (u16*)lB;
      const int cbase = wr*16;                // chunk base for this wave's rows
#pragma unroll
      for (int mf=0; mf<4; mf++)
#pragma unroll
        for (int nf=0; nf<4; nf++) {
          int d = nf*16 + lo;
          int c = cbase + mf*4 + hi;          // r-chunk (r = c*4 + i)
          u16x4 pk;
#pragma unroll
          for (int i=0;i<4;i++) pk[i] = f2h(acc[mf][nf][i] + bi[nf]);
          *(u16x4*)(Tt + d*128 + ((c ^ ((d & 7) << 2)) << 2)) = pk;
        }
      __syncthreads();
      // gather 8 l-consecutive elems per task, write 16B to vt
      const int hh0 = 2*by - 24;              // head for wc=0; +1 for wc=1
#pragma unroll
      for (int kq=0; kq<8; kq++) {
        int idx = tid + kq*256;               // [wcc][lh][d][nn], nn fastest
        int nn  = idx & 7;
        int d   = (idx >> 3) & 63;
        int lh  = (idx >> 9) & 1;
        int wcc = idx >> 10;
        const u16* Ts = (wcc == 0) ? (const u16*)lA : (const u16*)lB;
        u16x8 v8;
#pragma unroll
        for (int ll=0; ll<8; ll++) {
          int rl = (lh*8 + ll)*8 + nn;        // r_local = l_local*8 + n
          int c  = rl >> 2;
          v8[ll] = Ts[d*128 + ((c ^ ((d & 7) << 2)) << 2) + (rl & 3)];
        }
        size_t off = (((size_t)nn*12 + hh0 + wcc)*64 + d)*1024 + (size_t)bx*16 + lh*8;
        *(u16x8*)(vtp + off) = v8;
      }
    } else {
      // ---- q/k: fused row-normalize + scatter ----
      const int c0 = j0 - p*768;
      const int hh = c0 >> 6;
      u16* dst = (p==0) ? qh : kh;
      float qsc = 1.0f;
      if (p == 0) qsc = __expf(fminf(lsb[hh], 4.6051701859880913680f)) * 1.4426950408889634f;
#pragma unroll
      for (int mf=0; mf<4; mf++)
#pragma unroll
        for (int i=0;i<4;i++) {
          int r = r0 + mf*16 + 4*hi + i;
          int n = r & 7, l = r >> 3;
          float v[4]; float ss = 0.f;
#pragma unroll
          for (int nf=0;nf<4;nf++){ v[nf] = acc[mf][nf][i] + bi[nf]; ss += v[nf]*v[nf]; }
          ss += __shfl_xor(ss, 1);
          ss += __shfl_xor(ss, 2);
          ss += __shfl_xor(ss, 4);
          ss += __shfl_xor(ss, 8);
          float sc = qsc / fmaxf(sqrtf(ss), 1e-12f);
          size_t base = (((size_t)n*12 + hh)*1024 + l)*64;
#pragma unroll
          for (int nf=0;nf<4;nf++)
            dst[base + nf*16 + lo] = f2h(v[nf]*sc);
        }
    }
  } else {
#pragma unroll
    for (int nf=0; nf<4; nf++) {
      int j = j0 + nf*16 + lo;
      float bi = bias[j];
#pragma unroll
      for (int mf=0; mf<4; mf++)
#pragma unroll
        for (int i=0;i<4;i++) {
          int r = r0 + mf*16 + 4*hi + i;
          outp[(size_t)r*768 + j] = acc[mf][nf][i] + bi;
        }
    }
  }
}

// ---------------- flash attention (cosine-bounded: no running max needed) ----------------
// LDS-throughput analysis (R12): each wave read 16 x ds_read_b128 (16KB) per iter
// for only 16 q-rows -> ~30us of pure LDS issue at 24 waves/CU. Fix: 32 q-rows
// per wave (2 groups a/b) -> K-frag and V-frag reads each serve TWO accumulator
// sets -> LDS bytes per q-row HALVED. Grid (8 q-tiles, 96 nh) = 768 blocks =
// 3 blocks/CU (12 waves; LDS-BW-bound, not occupancy-bound). K/V re-read per
// (n,h) drops 16 -> 8 blocks (FETCH halves). __launch_bounds__(256,3): VGPR cap
// 170 >= ~140 needed - no spill (R9 lesson: watch VGPR_Count/WRITE_SIZE).
// Same R8-proven tile layout: XOR-swizzled [64][64] K and permuted VT, raw
// s_barrier + lgkmcnt(0), reg-staged global prefetch in flight across barriers.
__global__ __launch_bounds__(256, 3) void flash_kernel(
    const u16* __restrict__ qh, const u16* __restrict__ kh, const u16* __restrict__ vt,
    u16* __restrict__ obuf, const float* __restrict__ hsv, const float* __restrict__ lsp)
{
  __shared__ u16 lK[64*64];    // [k][d] swizzled 16B slots
  __shared__ u16 lVT[64*64];   // [d][k] permuted+swizzled 8B chunks
  // XCD-locality remap: 12 heads x 8 q-tiles per XCD (3MB K+V resident in L2)
  const int lin = blockIdx.y*8 + blockIdx.x;
  const int xcd = lin & 7, g = lin >> 3;
  const int nh = xcd + 8*(g >> 3);
  const int qt = g & 7;
  const int h = nh % 12, n = nh / 12;
  const u16* Qp = qh + (size_t)nh*65536;
  const u16* Kp = kh + (size_t)nh*65536;
  const u16* Vp = vt + (size_t)nh*65536;
  const int tid = threadIdx.x, lane = tid & 63, w = tid >> 6;
  const int lo = lane & 15, hi = lane >> 4;
  const int e = lo & 7;

  // Q fragments, both q-groups: lane holds Q[q=lo(+16)][d = hi*8 + j] (+32)
  h8 qa0, qa1, qb0, qb1;
  {
    const u16* qrow = Qp + (size_t)(qt*128 + w*32 + lo)*64 + hi*8;
    qa0 = *(const h8*)qrow;          qa1 = *(const h8*)(qrow + 32);
    qb0 = *(const h8*)(qrow + 1024); qb1 = *(const h8*)(qrow + 1024 + 32);
  }
  const f32x4 zero = {0.f,0.f,0.f,0.f};
  f32x4 oA[4] = {zero,zero,zero,zero};   // O^T[d=db*16+4hi+i][q=lo]
  f32x4 oB[4] = {zero,zero,zero,zero};
  f32x4 lA4 = zero, lB4 = zero;          // row sums via ones-MFMA
  const h4 ones = {(f16)1.f,(f16)1.f,(f16)1.f,(f16)1.f};

  // fp16-overflow guard (0 for these inputs; uniform branch if ever nonzero)
  float OFF;
  {
    float b = __expf(fminf(lsp[h], 4.6051701859880913680f)) * 1.4426950408889634f;
    OFF = fmaxf(b - 15.5f, 0.f);
  }

  const int sr = tid >> 2;          // stage row (k for lK, d for lVT), 0..63
  const int c4 = tid & 3;           // stage 16B-column group
  const int sx1 = sr & 7;           // K slot16 XOR
  const int sx2 = (sr & 7) << 1;    // VT chunk8 XOR (even)

  u32x4 ka, kb, va, vb;
  ka = *(const u32x4*)(Kp + (size_t)sr*64 + c4*16);
  kb = *(const u32x4*)(Kp + (size_t)sr*64 + c4*16 + 8);
  va = *(const u32x4*)(Vp + (size_t)sr*1024 + c4*16);
  vb = *(const u32x4*)(Vp + (size_t)sr*1024 + c4*16 + 8);

  for (int t = 0; t < 16; ++t) {
    // ---- stage regs -> LDS (swizzled) ----
    {
      u16* kr = lK + sr*64;
      *(u32x4*)(kr + (((2*c4)   ^ sx1) << 3)) = ka;
      *(u32x4*)(kr + (((2*c4+1) ^ sx1) << 3)) = kb;
      u16* vr = lVT + sr*64;
      *(u32x2*)(vr + (((( 0|c4) ^ sx2) << 2))) = (u32x2){va[0], va[1]};
      *(u32x2*)(vr + (((( 4|c4) ^ sx2) << 2))) = (u32x2){va[2], va[3]};
      *(u32x2*)(vr + (((( 8|c4) ^ sx2) << 2))) = (u32x2){vb[0], vb[1]};
      *(u32x2*)(vr + ((((12|c4) ^ sx2) << 2))) = (u32x2){vb[2], vb[3]};
    }
    asm volatile("s_waitcnt lgkmcnt(0)" ::: "memory");
    __builtin_amdgcn_sched_barrier(0);
    __builtin_amdgcn_s_barrier();                // tile visible to all waves
    if (t < 15) {  // prefetch next tile into regs; stays in flight across barrier
      ka = *(const u32x4*)(Kp + (size_t)(t+1)*4096 + (size_t)sr*64 + c4*16);
      kb = *(const u32x4*)(Kp + (size_t)(t+1)*4096 + (size_t)sr*64 + c4*16 + 8);
      va = *(const u32x4*)(Vp + (size_t)sr*1024 + (t+1)*64 + c4*16);
      vb = *(const u32x4*)(Vp + (size_t)sr*1024 + (t+1)*64 + c4*16 + 8);
    }
    // ---- S^T = K . Q^T, both q-groups (K fragments read ONCE, used twice) ----
    f32x4 sa[4], sb[4];
#pragma unroll
    for (int kf=0; kf<4; kf++) {
      const u16* krow = lK + (kf*16 + lo)*64;
      h8 k0 = *(const h8*)(krow + (((hi  ) ^ e) << 3));
      h8 k1 = *(const h8*)(krow + (((hi+4) ^ e) << 3));
      sa[kf] = MFMA32(k1, qa1, MFMA32(k0, qa0, zero));
      sb[kf] = MFMA32(k1, qb1, MFMA32(k0, qb0, zero));
    }
    if (OFF != 0.f) {
#pragma unroll
      for (int kf=0;kf<4;kf++)
#pragma unroll
        for (int i=0;i<4;i++) { sa[kf][i] -= OFF; sb[kf][i] -= OFF; }
    }
    // ---- p = exp2(s), packed into mfma16 B-operand layout ----
    h4 pa[4], pb[4];
#pragma unroll
    for (int kf=0;kf<4;kf++) {
      h2 a01 = pkrtz(fast_exp2(sa[kf][0]), fast_exp2(sa[kf][1]));
      h2 a23 = pkrtz(fast_exp2(sa[kf][2]), fast_exp2(sa[kf][3]));
      pa[kf] = __builtin_shufflevector(a01, a23, 0, 1, 2, 3);
      h2 b01 = pkrtz(fast_exp2(sb[kf][0]), fast_exp2(sb[kf][1]));
      h2 b23 = pkrtz(fast_exp2(sb[kf][2]), fast_exp2(sb[kf][3]));
      pb[kf] = __builtin_shufflevector(b01, b23, 0, 1, 2, 3);
    }
    // ---- row sums on the matrix pipe ----
#pragma unroll
    for (int kf=0;kf<4;kf++) {
      lA4 = MFMA16(ones, pa[kf], lA4);
      lB4 = MFMA16(ones, pb[kf], lB4);
    }
    // ---- PV: O^T += VT-frag x P-frag (V fragments read ONCE, used twice) ----
#pragma unroll
    for (int db=0; db<4; db++) {
      const u16* vrow = lVT + (db*16 + lo)*64;
      h8 v01 = *(const h8*)(vrow + ((((2*hi  ) ^ e) << 3)));
      h8 v23 = *(const h8*)(vrow + ((((2*hi+1) ^ e) << 3)));
      h4 f0 = __builtin_shufflevector(v01, v01, 0,1,2,3);
      h4 f1 = __builtin_shufflevector(v01, v01, 4,5,6,7);
      h4 f2 = __builtin_shufflevector(v23, v23, 0,1,2,3);
      h4 f3 = __builtin_shufflevector(v23, v23, 4,5,6,7);
      oA[db] = MFMA16(f0, pa[0], oA[db]);
      oB[db] = MFMA16(f0, pb[0], oB[db]);
      oA[db] = MFMA16(f1, pa[1], oA[db]);
      oB[db] = MFMA16(f1, pb[1], oB[db]);
      oA[db] = MFMA16(f2, pa[2], oA[db]);
      oB[db] = MFMA16(f2, pb[2], oB[db]);
      oA[db] = MFMA16(f3, pa[3], oA[db]);
      oB[db] = MFMA16(f3, pb[3], oB[db]);
    }
    asm volatile("s_waitcnt lgkmcnt(0)" ::: "memory"); // my reads retired
    __builtin_amdgcn_sched_barrier(0);
    __builtin_amdgcn_s_barrier();                      // safe to restage
  }
  // epilogue: O[q][d] = O^T / l * head_scale, store fp16 into (L,N,C)
  float hsc = hsv[h];
  float invA = hsc / lA4[0];
  float invB = hsc / lB4[0];
  int l0 = qt*128 + w*32 + lo;
  u16* dA = obuf + ((size_t)l0*8 + n)*768 + h*64;
  u16* dB = obuf + ((size_t)(l0+16)*8 + n)*768 + h*64;
#pragma unroll
  for (int db=0; db<4; db++) {
    u16x4 pk0, pk1;
#pragma unroll
    for (int i=0;i<4;i++) { pk0[i] = f2h(oA[db][i]*invA); pk1[i] = f2h(oB[db][i]*invB); }
    *(u16x4*)(dA + db*16 + hi*4) = pk0;
    *(u16x4*)(dB + db*16 + hi*4) = pk1;
  }
}

extern "C" void kernel_launch(void* const* d_in, const int* in_sizes, int n_in,
                              void* d_out, int out_size, void* d_ws, size_t ws_size,
                              hipStream_t stream)
{
  (void)in_sizes; (void)n_in; (void)out_size; (void)ws_size;
  const float* x  = (const float*)d_in[0];
  const float* w1 = (const float*)d_in[1];
  const float* b1 = (const float*)d_in[2];
  const float* ls = (const float*)d_in[3];
  const float* hs = (const float*)d_in[4];
  const float* w2 = (const float*)d_in[5];
  const float* b2 = (const float*)d_in[6];
  float* out = (float*)d_out;

  u16* x_bf  = (u16*)d_ws;            // 8192 x 768  (reused as ob after GEMM1)
  u16* w1_bf = x_bf  + 6291456;       // 2304 x 768
  u16* w2_bf = w1_bf + 1769472;       // 768 x 768
  u16* qh    = w2_bf + 589824;        // (N,H,L,D) normalized (+ls*log2e on q)
  u16* kh    = qh    + 6291456;
  u16* vt    = kh    + 6291456;       // (N,H,D,L) — written directly by gemm1
  u16* ob    = x_bf;                  // (L,N,C) fp16, aliases x_bf

  cvt3_kernel<<<8448, 256, 0, stream>>>(x, x_bf, w1, w1_bf, w2, w2_bf);
  gemm_kernel<<<dim3(64,18), 256, 0, stream>>>(x_bf, w1_bf, b1, 0, qh, kh, vt, nullptr, ls);
  flash_kernel<<<dim3(8,96), 256, 0, stream>>>(qh, kh, vt, ob, hs, ls);
  gemm_kernel<<<dim3(64,6), 256, 0, stream>>>(ob, w2_bf, b2, 1, nullptr, nullptr, nullptr, out, ls);
}

// Round 14
// 117.407 us; speedup vs baseline: 1.1371x; 1.0074x over previous
//
#include <hip/hip_runtime.h>
#include <stdint.h>
#include <math.h>

typedef unsigned short u16;
typedef _Float16 f16;
typedef __attribute__((ext_vector_type(4))) float f32x4;
typedef __attribute__((ext_vector_type(8))) f16 h8;
typedef __attribute__((ext_vector_type(4))) f16 h4;
typedef __attribute__((ext_vector_type(2))) f16 h2;
typedef __attribute__((ext_vector_type(2))) __fp16 fp16x2;
typedef __attribute__((ext_vector_type(2))) unsigned int u32x2;
typedef __attribute__((ext_vector_type(4))) unsigned int u32x4;
typedef __attribute__((ext_vector_type(4))) unsigned short u16x4;
typedef __attribute__((ext_vector_type(8))) unsigned short u16x8;

typedef const __attribute__((address_space(1))) u16 gas_u16;
typedef __attribute__((address_space(3))) u16 las_u16;

#define MFMA32(a,b,c) __builtin_amdgcn_mfma_f32_16x16x32_f16((a),(b),(c),0,0,0)
#define MFMA16(a,b,c) __builtin_amdgcn_mfma_f32_16x16x16f16((a),(b),(c),0,0,0)

__device__ __forceinline__ float h2f(u16 h){ f16 x; __builtin_memcpy(&x,&h,2); return (float)x; }
__device__ __forceinline__ u16 f2h(float f){ f16 x = (f16)f; u16 u; __builtin_memcpy(&u,&x,2); return u; }

__device__ __forceinline__ float fast_exp2(float x){
#if __has_builtin(__builtin_amdgcn_exp2f)
  return __builtin_amdgcn_exp2f(x);
#else
  return exp2f(x);
#endif
}

// pack two f32 -> two f16 in one v_cvt_pkrtz; bit-cast to _Float16 vector type
__device__ __forceinline__ h2 pkrtz(float a, float b){
  fp16x2 t = __builtin_amdgcn_cvt_pkrtz(a, b);
  h2 r; __builtin_memcpy(&r, &t, 4);
  return r;
}

// ---------------- fused fp32 -> fp16 convert (x, w1, w2 in one launch) ----------------
#define NA4 1572864
#define NB4 442368
#define NC4 147456
__global__ __launch_bounds__(256) void cvt3_kernel(
    const float* __restrict__ a, u16* __restrict__ da,
    const float* __restrict__ b, u16* __restrict__ db,
    const float* __restrict__ c, u16* __restrict__ dc)
{
  int i = blockIdx.x*256 + threadIdx.x;
  const float* s; u16* d; int off;
  if (i < NA4)            { s = a; d = da; off = i; }
  else if (i < NA4+NB4)   { s = b; d = db; off = i - NA4; }
  else if (i < NA4+NB4+NC4){ s = c; d = dc; off = i - NA4 - NB4; }
  else return;
  f32x4 v = ((const f32x4*)s)[off];
  u16x4 o;
  o[0]=f2h(v[0]); o[1]=f2h(v[1]); o[2]=f2h(v[2]); o[3]=f2h(v[3]);
  ((u16x4*)d)[off] = o;
}

// ---------------- fp16 GEMM, C = A(M x 768) * B(N x 768)^T + bias ----------------
// R8-proven main loop: T4 counted-vmcnt dbuf at BK=64 (12 K-steps, vmcnt(8),
// raw s_barrier). transpose fused into the mode-0 V epilogue (round 12, kept).
// NEW (R14): wave-staggered kk order (kk = s ^ (w&1)) — barrier lockstep made
// all 4 waves burst LDS then burst MFMA simultaneously (per-iter wall = SUM of
// pipe bursts, all pipes ~20%); staggering interleaves half the waves' LDS burst
// with the other half's MFMA burst. fp-sum reorder only, within tolerance.
// mode 0: q/k row-normalize (+ logit_scale*log2e on q) scatter + V transpose.
// mode 1: fp32 out (M x 768).
__global__ __launch_bounds__(256) void gemm_kernel(
    const u16* __restrict__ A, const u16* __restrict__ B, const float* __restrict__ bias,
    int mode, u16* __restrict__ qh, u16* __restrict__ kh, u16* __restrict__ vtp,
    float* __restrict__ outp, const float* __restrict__ lsb)
{
  __shared__ u16 lA[2][128*64];   // [buf][row(128)][slot(8) of 16B], swizzled slots
  __shared__ u16 lB[2][128*64];
  const int tid = threadIdx.x;
  const int lane = tid & 63;
  const int w = tid >> 6, wr = w >> 1, wc = w & 1;
  const int lo = lane & 15, hi = lane >> 4;

  const int bx = blockIdx.x, by = blockIdx.y;

  f32x4 zero = {0.f,0.f,0.f,0.f};
  f32x4 acc[4][4];
#pragma unroll
  for (int a=0;a<4;a++)
#pragma unroll
    for (int b=0;b<4;b++) acc[a][b] = zero;
  const u16* Ag = A + (size_t)bx*128*768;
  const u16* Bg = B + (size_t)by*128*768;
  const int srow = tid >> 3;                         // 0..31 (+j*32)
  const int scol = (((tid & 7) ^ (srow & 7)) * 8);   // pre-swizzled source 16B-slot

#define STAGE(buf, kt) do { \
    _Pragma("unroll") \
    for (int j=0;j<4;j++) { \
      __builtin_amdgcn_global_load_lds((gas_u16*)(Ag + (size_t)(j*32+srow)*768 + (kt) + scol), (las_u16*)(&lA[buf][j*2048 + tid*8]), 16, 0, 0); \
      __builtin_amdgcn_global_load_lds((gas_u16*)(Bg + (size_t)(j*32+srow)*768 + (kt) + scol), (las_u16*)(&lB[buf][j*2048 + tid*8]), 16, 0, 0); \
    } \
  } while(0)

  STAGE(0, 0);
#pragma unroll
  for (int t = 0; t < 12; ++t) {
    const int cur = t & 1;
    if (t < 11) {
      STAGE(cur^1, (t+1)*64);                         // next tile: 8 loads in flight
      asm volatile("s_waitcnt vmcnt(8)" ::: "memory"); // current tile landed
    } else {
      asm volatile("s_waitcnt vmcnt(0)" ::: "memory");
    }
    __builtin_amdgcn_sched_barrier(0);
    __builtin_amdgcn_s_barrier();                     // no implicit drain
#pragma unroll
    for (int s=0;s<2;s++) {
      const int kk = s ^ (w & 1);                     // wave-staggered half order
      h8 af[4], bfr[4];
#pragma unroll
      for (int mf=0; mf<4; mf++) {
        int r = wr*64 + mf*16 + lo;
        af[mf]  = *(const h8*)(&lA[cur][r*64 + (((hi + 4*kk) ^ (lo & 7)) * 8)]);
      }
#pragma unroll
      for (int nf=0; nf<4; nf++) {
        int r = wc*64 + nf*16 + lo;
        bfr[nf] = *(const h8*)(&lB[cur][r*64 + (((hi + 4*kk) ^ (lo & 7)) * 8)]);
      }
#pragma unroll
      for (int mf=0; mf<4; mf++)
#pragma unroll
        for (int nf=0; nf<4; nf++)
          acc[mf][nf] = MFMA32(af[mf], bfr[nf], acc[mf][nf]);
    }
    asm volatile("s_waitcnt lgkmcnt(0)" ::: "memory"); // my reads of cur retired
    __builtin_amdgcn_sched_barrier(0);
    __builtin_amdgcn_s_barrier();                      // now cur may be restaged
  }
#undef STAGE

  const int r0 = bx*128 + wr*64;
  const int j0 = by*128 + wc*64;
  if (mode == 0) {
    const int p = (j0 >= 1536) ? 2 : ((j0 >= 768) ? 1 : 0);
    float bi[4];
#pragma unroll
    for (int nf=0;nf<4;nf++) bi[nf] = bias[j0 + nf*16 + lo];
    if (p == 2) {
      // ---- V: transposed store via dead staging LDS ----
      u16* Tt = (wc == 0) ? (u16*)lA : (u16*)lB;
      const int cbase = wr*16;                // chunk base for this wave's rows
#pragma unroll
      for (int mf=0; mf<4; mf++)
#pragma unroll
        for (int nf=0; nf<4; nf++) {
          int d = nf*16 + lo;
          int c = cbase + mf*4 + hi;          // r-chunk (r = c*4 + i)
          u16x4 pk;
#pragma unroll
          for (int i=0;i<4;i++) pk[i] = f2h(acc[mf][nf][i] + bi[nf]);
          *(u16x4*)(Tt + d*128 + ((c ^ ((d & 7) << 2)) << 2)) = pk;
        }
      __syncthreads();
      const int hh0 = 2*by - 24;              // head for wc=0; +1 for wc=1
#pragma unroll
      for (int kq=0; kq<8; kq++) {
        int idx = tid + kq*256;               // [wcc][lh][d][nn], nn fastest
        int nn  = idx & 7;
        int d   = (idx >> 3) & 63;
        int lh  = (idx >> 9) & 1;
        int wcc = idx >> 10;
        const u16* Ts = (wcc == 0) ? (const u16*)lA : (const u16*)lB;
        u16x8 v8;
#pragma unroll
        for (int ll=0; ll<8; ll++) {
          int rl = (lh*8 + ll)*8 + nn;        // r_local = l_local*8 + n
          int c  = rl >> 2;
          v8[ll] = Ts[d*128 + ((c ^ ((d & 7) << 2)) << 2) + (rl & 3)];
        }
        size_t off = (((size_t)nn*12 + hh0 + wcc)*64 + d)*1024 + (size_t)bx*16 + lh*8;
        *(u16x8*)(vtp + off) = v8;
      }
    } else {
      // ---- q/k: fused row-normalize + scatter ----
      const int c0 = j0 - p*768;
      const int hh = c0 >> 6;
      u16* dst = (p==0) ? qh : kh;
      float qsc = 1.0f;
      if (p == 0) qsc = __expf(fminf(lsb[hh], 4.6051701859880913680f)) * 1.4426950408889634f;
#pragma unroll
      for (int mf=0; mf<4; mf++)
#pragma unroll
        for (int i=0;i<4;i++) {
          int r = r0 + mf*16 + 4*hi + i;
          int n = r & 7, l = r >> 3;
          float v[4]; float ss = 0.f;
#pragma unroll
          for (int nf=0;nf<4;nf++){ v[nf] = acc[mf][nf][i] + bi[nf]; ss += v[nf]*v[nf]; }
          ss += __shfl_xor(ss, 1);
          ss += __shfl_xor(ss, 2);
          ss += __shfl_xor(ss, 4);
          ss += __shfl_xor(ss, 8);
          float sc = qsc / fmaxf(sqrtf(ss), 1e-12f);
          size_t base = (((size_t)n*12 + hh)*1024 + l)*64;
#pragma unroll
          for (int nf=0;nf<4;nf++)
            dst[base + nf*16 + lo] = f2h(v[nf]*sc);
        }
    }
  } else {
#pragma unroll
    for (int nf=0; nf<4; nf++) {
      int j = j0 + nf*16 + lo;
      float bi = bias[j];
#pragma unroll
      for (int mf=0; mf<4; mf++)
#pragma unroll
        for (int i=0;i<4;i++) {
          int r = r0 + mf*16 + 4*hi + i;
          outp[(size_t)r*768 + j] = acc[mf][nf][i] + bi;
        }
    }
  }
}

// ---------------- flash attention (cosine-bounded: no running max needed) ----------------
// R13 structure (32 q-rows/wave, shared K/V frags) + NEW (R14): double-buffered
// K/VT tiles -> ONE lgkm+barrier per iteration (was 2+2). Order per iter:
// global-prefetch t+1 (issued FIRST, lands under compute) -> compute from
// buf[t&1] -> ds_write t+1 into buf[t&1^1] (no WAR: other buffer) -> lgkm(0)
// (my ds_writes visible) -> s_barrier. LDS 2x16KB = 32KB, still 3 blocks/CU.
__global__ __launch_bounds__(256, 3) void flash_kernel(
    const u16* __restrict__ qh, const u16* __restrict__ kh, const u16* __restrict__ vt,
    u16* __restrict__ obuf, const float* __restrict__ hsv, const float* __restrict__ lsp)
{
  __shared__ u16 lK[2][64*64];    // [buf][k][d] swizzled 16B slots
  __shared__ u16 lVT[2][64*64];   // [buf][d][k] permuted+swizzled 8B chunks
  // XCD-locality remap: 12 heads x 8 q-tiles per XCD (3MB K+V resident in L2)
  const int lin = blockIdx.y*8 + blockIdx.x;
  const int xcd = lin & 7, g = lin >> 3;
  const int nh = xcd + 8*(g >> 3);
  const int qt = g & 7;
  const int h = nh % 12, n = nh / 12;
  const u16* Qp = qh + (size_t)nh*65536;
  const u16* Kp = kh + (size_t)nh*65536;
  const u16* Vp = vt + (size_t)nh*65536;
  const int tid = threadIdx.x, lane = tid & 63, w = tid >> 6;
  const int lo = lane & 15, hi = lane >> 4;
  const int e = lo & 7;

  // Q fragments, both q-groups: lane holds Q[q=lo(+16)][d = hi*8 + j] (+32)
  h8 qa0, qa1, qb0, qb1;
  {
    const u16* qrow = Qp + (size_t)(qt*128 + w*32 + lo)*64 + hi*8;
    qa0 = *(const h8*)qrow;          qa1 = *(const h8*)(qrow + 32);
    qb0 = *(const h8*)(qrow + 1024); qb1 = *(const h8*)(qrow + 1024 + 32);
  }
  const f32x4 zero = {0.f,0.f,0.f,0.f};
  f32x4 oA[4] = {zero,zero,zero,zero};   // O^T[d=db*16+4hi+i][q=lo]
  f32x4 oB[4] = {zero,zero,zero,zero};
  f32x4 lA4 = zero, lB4 = zero;          // row sums via ones-MFMA
  const h4 ones = {(f16)1.f,(f16)1.f,(f16)1.f,(f16)1.f};

  // fp16-overflow guard (0 for these inputs; uniform branch if ever nonzero)
  float OFF;
  {
    float b = __expf(fminf(lsp[h], 4.6051701859880913680f)) * 1.4426950408889634f;
    OFF = fmaxf(b - 15.5f, 0.f);
  }

  const int sr = tid >> 2;          // stage row (k for lK, d for lVT), 0..63
  const int c4 = tid & 3;           // stage 16B-column group
  const int sx1 = sr & 7;           // K slot16 XOR
  const int sx2 = (sr & 7) << 1;    // VT chunk8 XOR (even)

  u32x4 ka, kb, va, vb;
  ka = *(const u32x4*)(Kp + (size_t)sr*64 + c4*16);
  kb = *(const u32x4*)(Kp + (size_t)sr*64 + c4*16 + 8);
  va = *(const u32x4*)(Vp + (size_t)sr*1024 + c4*16);
  vb = *(const u32x4*)(Vp + (size_t)sr*1024 + c4*16 + 8);

#define STAGE_WRITE(bf) do { \
    u16* kr = lK[bf] + sr*64; \
    *(u32x4*)(kr + (((2*c4)   ^ sx1) << 3)) = ka; \
    *(u32x4*)(kr + (((2*c4+1) ^ sx1) << 3)) = kb; \
    u16* vr = lVT[bf] + sr*64; \
    *(u32x2*)(vr + (((( 0|c4) ^ sx2) << 2))) = (u32x2){va[0], va[1]}; \
    *(u32x2*)(vr + (((( 4|c4) ^ sx2) << 2))) = (u32x2){va[2], va[3]}; \
    *(u32x2*)(vr + (((( 8|c4) ^ sx2) << 2))) = (u32x2){vb[0], vb[1]}; \
    *(u32x2*)(vr + ((((12|c4) ^ sx2) << 2))) = (u32x2){vb[2], vb[3]}; \
  } while(0)

  STAGE_WRITE(0);
  asm volatile("s_waitcnt lgkmcnt(0)" ::: "memory");
  __builtin_amdgcn_sched_barrier(0);
  __builtin_amdgcn_s_barrier();

  for (int t = 0; t < 16; ++t) {
    const int cb = t & 1;
    if (t < 15) {  // prefetch next tile into regs; lands under this iter's compute
      ka = *(const u32x4*)(Kp + (size_t)(t+1)*4096 + (size_t)sr*64 + c4*16);
      kb = *(const u32x4*)(Kp + (size_t)(t+1)*4096 + (size_t)sr*64 + c4*16 + 8);
      va = *(const u32x4*)(Vp + (size_t)sr*1024 + (t+1)*64 + c4*16);
      vb = *(const u32x4*)(Vp + (size_t)sr*1024 + (t+1)*64 + c4*16 + 8);
    }
    // ---- S^T = K . Q^T, both q-groups (K fragments read ONCE, used twice) ----
    f32x4 sa[4], sb[4];
#pragma unroll
    for (int kf=0; kf<4; kf++) {
      const u16* krow = lK[cb] + (kf*16 + lo)*64;
      h8 k0 = *(const h8*)(krow + (((hi  ) ^ e) << 3));
      h8 k1 = *(const h8*)(krow + (((hi+4) ^ e) << 3));
      sa[kf] = MFMA32(k1, qa1, MFMA32(k0, qa0, zero));
      sb[kf] = MFMA32(k1, qb1, MFMA32(k0, qb0, zero));
    }
    if (OFF != 0.f) {
#pragma unroll
      for (int kf=0;kf<4;kf++)
#pragma unroll
        for (int i=0;i<4;i++) { sa[kf][i] -= OFF; sb[kf][i] -= OFF; }
    }
    // ---- p = exp2(s), packed into mfma16 B-operand layout ----
    h4 pa[4], pb[4];
#pragma unroll
    for (int kf=0;kf<4;kf++) {
      h2 a01 = pkrtz(fast_exp2(sa[kf][0]), fast_exp2(sa[kf][1]));
      h2 a23 = pkrtz(fast_exp2(sa[kf][2]), fast_exp2(sa[kf][3]));
      pa[kf] = __builtin_shufflevector(a01, a23, 0, 1, 2, 3);
      h2 b01 = pkrtz(fast_exp2(sb[kf][0]), fast_exp2(sb[kf][1]));
      h2 b23 = pkrtz(fast_exp2(sb[kf][2]), fast_exp2(sb[kf][3]));
      pb[kf] = __builtin_shufflevector(b01, b23, 0, 1, 2, 3);
    }
    // ---- row sums on the matrix pipe ----
#pragma unroll
    for (int kf=0;kf<4;kf++) {
      lA4 = MFMA16(ones, pa[kf], lA4);
      lB4 = MFMA16(ones, pb[kf], lB4);
    }
    // ---- PV: O^T += VT-frag x P-frag (V fragments read ONCE, used twice) ----
#pragma unroll
    for (int db=0; db<4; db++) {
      const u16* vrow = lVT[cb] + (db*16 + lo)*64;
      h8 v01 = *(const h8*)(vrow + ((((2*hi  ) ^ e) << 3)));
      h8 v23 = *(const h8*)(vrow + ((((2*hi+1) ^ e) << 3)));
      h4 f0 = __builtin_shufflevector(v01, v01, 0,1,2,3);
      h4 f1 = __builtin_shufflevector(v01, v01, 4,5,6,7);
      h4 f2 = __builtin_shufflevector(v23, v23, 0,1,2,3);
      h4 f3 = __builtin_shufflevector(v23, v23, 4,5,6,7);
      oA[db] = MFMA16(f0, pa[0], oA[db]);
      oB[db] = MFMA16(f0, pb[0], oB[db]);
      oA[db] = MFMA16(f1, pa[1], oA[db]);
      oB[db] = MFMA16(f1, pb[1], oB[db]);
      oA[db] = MFMA16(f2, pa[2], oA[db]);
      oB[db] = MFMA16(f2, pb[2], oB[db]);
      oA[db] = MFMA16(f3, pa[3], oA[db]);
      oB[db] = MFMA16(f3, pb[3], oB[db]);
    }
    // ---- write next tile into the OTHER buffer; single barrier per iter ----
    if (t < 15) STAGE_WRITE(cb ^ 1);
    asm volatile("s_waitcnt lgkmcnt(0)" ::: "memory"); // my ds_writes visible
    __builtin_amdgcn_sched_barrier(0);
    __builtin_amdgcn_s_barrier();
  }
#undef STAGE_WRITE
  // epilogue: O[q][d] = O^T / l * head_scale, store fp16 into (L,N,C)
  float hsc = hsv[h];
  float invA = hsc / lA4[0];
  float invB = hsc / lB4[0];
  int l0 = qt*128 + w*32 + lo;
  u16* dA = obuf + ((size_t)l0*8 + n)*768 + h*64;
  u16* dB = obuf + ((size_t)(l0+16)*8 + n)*768 + h*64;
#pragma unroll
  for (int db=0; db<4; db++) {
    u16x4 pk0, pk1;
#pragma unroll
    for (int i=0;i<4;i++) { pk0[i] = f2h(oA[db][i]*invA); pk1[i] = f2h(oB[db][i]*invB); }
    *(u16x4*)(dA + db*16 + hi*4) = pk0;
    *(u16x4*)(dB + db*16 + hi*4) = pk1;
  }
}

extern "C" void kernel_launch(void* const* d_in, const int* in_sizes, int n_in,
                              void* d_out, int out_size, void* d_ws, size_t ws_size,
                              hipStream_t stream)
{
  (void)in_sizes; (void)n_in; (void)out_size; (void)ws_size;
  const float* x  = (const float*)d_in[0];
  const float* w1 = (const float*)d_in[1];
  const float* b1 = (const float*)d_in[2];
  const float* ls = (const float*)d_in[3];
  const float* hs = (const float*)d_in[4];
  const float* w2 = (const float*)d_in[5];
  const float* b2 = (const float*)d_in[6];
  float* out = (float*)d_out;

  u16* x_bf  = (u16*)d_ws;            // 8192 x 768  (reused as ob after GEMM1)
  u16* w1_bf = x_bf  + 6291456;       // 2304 x 768
  u16* w2_bf = w1_bf + 1769472;       // 768 x 768
  u16* qh    = w2_bf + 589824;        // (N,H,L,D) normalized (+ls*log2e on q)
  u16* kh    = qh    + 6291456;
  u16* vt    = kh    + 6291456;       // (N,H,D,L) — written directly by gemm1
  u16* ob    = x_bf;                  // (L,N,C) fp16, aliases x_bf

  cvt3_kernel<<<8448, 256, 0, stream>>>(x, x_bf, w1, w1_bf, w2, w2_bf);
  gemm_kernel<<<dim3(64,18), 256, 0, stream>>>(x_bf, w1_bf, b1, 0, qh, kh, vt, nullptr, ls);
  flash_kernel<<<dim3(8,96), 256, 0, stream>>>(qh, kh, vt, ob, hs, ls);
  gemm_kernel<<<dim3(64,6), 256, 0, stream>>>(ob, w2_bf, b2, 1, nullptr, nullptr, nullptr, out, ls);
}

// Round 15
// 114.358 us; speedup vs baseline: 1.1675x; 1.0267x over previous
//
#include <hip/hip_runtime.h>
#include <stdint.h>
#include <math.h>

typedef unsigned short u16;
typedef _Float16 f16;
typedef __attribute__((ext_vector_type(4))) float f32x4;
typedef __attribute__((ext_vector_type(8))) f16 h8;
typedef __attribute__((ext_vector_type(4))) f16 h4;
typedef __attribute__((ext_vector_type(2))) f16 h2;
typedef __attribute__((ext_vector_type(2))) __fp16 fp16x2;
typedef __attribute__((ext_vector_type(2))) unsigned int u32x2;
typedef __attribute__((ext_vector_type(4))) unsigned int u32x4;
typedef __attribute__((ext_vector_type(4))) unsigned short u16x4;
typedef __attribute__((ext_vector_type(8))) unsigned short u16x8;

typedef const __attribute__((address_space(1))) u16 gas_u16;
typedef __attribute__((address_space(3))) u16 las_u16;

#define MFMA32(a,b,c) __builtin_amdgcn_mfma_f32_16x16x32_f16((a),(b),(c),0,0,0)
#define MFMA16(a,b,c) __builtin_amdgcn_mfma_f32_16x16x16f16((a),(b),(c),0,0,0)

__device__ __forceinline__ float h2f(u16 h){ f16 x; __builtin_memcpy(&x,&h,2); return (float)x; }
__device__ __forceinline__ u16 f2h(float f){ f16 x = (f16)f; u16 u; __builtin_memcpy(&u,&x,2); return u; }

__device__ __forceinline__ float fast_exp2(float x){
#if __has_builtin(__builtin_amdgcn_exp2f)
  return __builtin_amdgcn_exp2f(x);
#else
  return exp2f(x);
#endif
}

// pack two f32 -> two f16 in one v_cvt_pkrtz; bit-cast to _Float16 vector type
__device__ __forceinline__ h2 pkrtz(float a, float b){
  fp16x2 t = __builtin_amdgcn_cvt_pkrtz(a, b);
  h2 r; __builtin_memcpy(&r, &t, 4);
  return r;
}

// ---------------- fused fp32 -> fp16 convert (x, w1, w2 in one launch) ----------------
#define NA4 1572864
#define NB4 442368
#define NC4 147456
__global__ __launch_bounds__(256) void cvt3_kernel(
    const float* __restrict__ a, u16* __restrict__ da,
    const float* __restrict__ b, u16* __restrict__ db,
    const float* __restrict__ c, u16* __restrict__ dc)
{
  int i = blockIdx.x*256 + threadIdx.x;
  const float* s; u16* d; int off;
  if (i < NA4)            { s = a; d = da; off = i; }
  else if (i < NA4+NB4)   { s = b; d = db; off = i - NA4; }
  else if (i < NA4+NB4+NC4){ s = c; d = dc; off = i - NA4 - NB4; }
  else return;
  f32x4 v = ((const f32x4*)s)[off];
  u16x4 o;
  o[0]=f2h(v[0]); o[1]=f2h(v[1]); o[2]=f2h(v[2]); o[3]=f2h(v[3]);
  ((u16x4*)d)[off] = o;
}

// ---------------- fp16 GEMM, C = A(M x 768) * B(N x 768)^T + bias ----------------
// R15: 8-phase-style schedule (T3+T4+T5), the structural change past the 52-55us
// 2-barrier plateau (R8-R14; m233: that structure is ~72% stage/vmcnt/barrier).
// BM=128 BN=256 BK=64, 512 threads = 8 waves (2M x 4N), per-wave 64x64 (same
// fragment geometry as before -> epilogues carried over). TRIPLE-buffered K-tile
// slots (3 x 48KB = 144KB, 1 block/CU, 2 waves/SIMD) -> depth-2 staging.
// 12 K-steps x 2 phases; per phase: 8 ds_read_b128 -> 3 global_load_lds ->
// s_barrier -> lgkm(0) -> setprio(1) 16 MFMA setprio(0) -> [vmcnt(6) at step
// end: waits tile t+1, leaves t+2's 6 loads in flight - NEVER drains to 0] ->
// s_barrier. Ledger: steady 12 outstanding; WAR: slot (t+2)%3 last read in step
// t-1, retired by its lgkm+barrier. Swizzle: R8-verified (slot p^(r&7), read at
// (hi+4kk)^(lo&7); 0 conflicts).
// mode 0: q/k row-normalize (+ logit_scale*log2e on q) scatter + V transpose.
// mode 1: fp32 out (M x 768).
#define GSLOT 24576   // u16 per slot: A 128*64 + B 256*64
__global__ __launch_bounds__(512, 2) void gemm_kernel(
    const u16* __restrict__ A, const u16* __restrict__ B, const float* __restrict__ bias,
    int mode, u16* __restrict__ qh, u16* __restrict__ kh, u16* __restrict__ vtp,
    float* __restrict__ outp, const float* __restrict__ lsb)
{
  __shared__ u16 L[3*GSLOT];      // 144KB
  const int tid = threadIdx.x;
  const int lane = tid & 63;
  const int w = tid >> 6;               // 0..7
  const int wm = w >> 2, wn = w & 3;    // 2M x 4N wave grid
  const int lo = lane & 15, hi = lane >> 4;

  const int bx = blockIdx.x, by = blockIdx.y;

  f32x4 zero = {0.f,0.f,0.f,0.f};
  f32x4 acc[4][4];
#pragma unroll
  for (int a=0;a<4;a++)
#pragma unroll
    for (int b=0;b<4;b++) acc[a][b] = zero;
  const u16* Ag = A + (size_t)bx*128*768;
  const u16* Bg = B + (size_t)by*256*768;
  const int srow = tid >> 3;                         // 0..63
  const int scol = (((tid & 7) ^ (srow & 7)) * 8);   // pre-swizzled source 16B-slot

  // half 0: A rows srow, srow+64 and B rows srow; half 1: B rows srow+64/128/192
#define STG(slot, kt, half) do { \
    if ((half) == 0) { \
      __builtin_amdgcn_global_load_lds((gas_u16*)(Ag + (size_t)srow*768 + (kt) + scol),      (las_u16*)(&L[(slot)*GSLOT + tid*8]),        16, 0, 0); \
      __builtin_amdgcn_global_load_lds((gas_u16*)(Ag + (size_t)(srow+64)*768 + (kt) + scol), (las_u16*)(&L[(slot)*GSLOT + 4096 + tid*8]), 16, 0, 0); \
      __builtin_amdgcn_global_load_lds((gas_u16*)(Bg + (size_t)srow*768 + (kt) + scol),      (las_u16*)(&L[(slot)*GSLOT + 8192 + tid*8]), 16, 0, 0); \
    } else { \
      __builtin_amdgcn_global_load_lds((gas_u16*)(Bg + (size_t)(srow+64)*768 + (kt) + scol),  (las_u16*)(&L[(slot)*GSLOT + 12288 + tid*8]), 16, 0, 0); \
      __builtin_amdgcn_global_load_lds((gas_u16*)(Bg + (size_t)(srow+128)*768 + (kt) + scol), (las_u16*)(&L[(slot)*GSLOT + 16384 + tid*8]), 16, 0, 0); \
      __builtin_amdgcn_global_load_lds((gas_u16*)(Bg + (size_t)(srow+192)*768 + (kt) + scol), (las_u16*)(&L[(slot)*GSLOT + 20480 + tid*8]), 16, 0, 0); \
    } \
  } while(0)

  STG(0, 0, 0);  STG(0, 0, 1);     // tile 0
  STG(1, 64, 0); STG(1, 64, 1);    // tile 1
  asm volatile("s_waitcnt vmcnt(6)" ::: "memory");   // tile 0 landed; tile 1 in flight
  __builtin_amdgcn_sched_barrier(0);
  __builtin_amdgcn_s_barrier();

  int cs = 0;                       // slot holding tile t
  for (int t = 0; t < 12; ++t) {
    const u16* LA = L + cs*GSLOT;
    const u16* LB = LA + 8192;
    int ss = cs + 2; if (ss >= 3) ss -= 3;   // slot for tile t+2
#pragma unroll
    for (int kk = 0; kk < 2; ++kk) {
      const int rsl = ((hi + 4*kk) ^ (lo & 7)) * 8;
      h8 af[4], bfr[4];
#pragma unroll
      for (int mf=0; mf<4; mf++) af[mf]  = *(const h8*)(LA + (wm*64 + mf*16 + lo)*64 + rsl);
#pragma unroll
      for (int nf=0; nf<4; nf++) bfr[nf] = *(const h8*)(LB + (wn*64 + nf*16 + lo)*64 + rsl);
      if (t < 10) STG(ss, (t+2)*64, kk);               // 3 loads per phase
      __builtin_amdgcn_s_barrier();                    // role-diversity barrier
      asm volatile("s_waitcnt lgkmcnt(0)" ::: "memory");
      __builtin_amdgcn_sched_barrier(0);
      __builtin_amdgcn_s_setprio(1);
#pragma unroll
      for (int mf=0; mf<4; mf++)
#pragma unroll
        for (int nf=0; nf<4; nf++)
          acc[mf][nf] = MFMA32(af[mf], bfr[nf], acc[mf][nf]);
      __builtin_amdgcn_s_setprio(0);
      if (kk == 1) {                                   // counted wait, once/step
        if (t < 10)       asm volatile("s_waitcnt vmcnt(6)" ::: "memory");
        else if (t == 10) asm volatile("s_waitcnt vmcnt(0)" ::: "memory");
        __builtin_amdgcn_sched_barrier(0);
      }
      __builtin_amdgcn_s_barrier();
    }
    cs += 1; if (cs >= 3) cs -= 3;
  }
#undef STG

  const int r0 = bx*128 + wm*64;
  const int j0 = by*256 + wn*64;
  if (mode == 0) {
    const int p = (j0 >= 1536) ? 2 : ((j0 >= 768) ? 1 : 0);
    float bi[4];
#pragma unroll
    for (int nf=0;nf<4;nf++) bi[nf] = bias[j0 + nf*16 + lo];
    if (p == 2) {
      // ---- V: transposed store via dead LDS; 4 per-wn tiles T[d(64)][r(128)] ----
      u16* Tt = (u16*)L + wn*8192;
#pragma unroll
      for (int mf=0; mf<4; mf++)
#pragma unroll
        for (int nf=0; nf<4; nf++) {
          int d = nf*16 + lo;
          int c = wm*16 + mf*4 + hi;          // r-chunk (r = c*4 + i), 0..31
          u16x4 pk;
#pragma unroll
          for (int i=0;i<4;i++) pk[i] = f2h(acc[mf][nf][i] + bi[nf]);
          *(u16x4*)(Tt + d*128 + ((c ^ ((d & 7) << 2)) << 2)) = pk;
        }
      __syncthreads();
      // gather 8 l-consecutive elems per task, write 16B to vt
#pragma unroll
      for (int kq=0; kq<8; kq++) {
        int idx = tid + kq*512;               // [tw][lh][d][nn], nn fastest
        int nn  = idx & 7;
        int d   = (idx >> 3) & 63;
        int lh  = (idx >> 9) & 1;
        int tw  = idx >> 10;                  // 0..3
        const u16* Ts = (const u16*)L + tw*8192;
        int hh = (by - 6)*4 + tw;
        u16x8 v8;
#pragma unroll
        for (int ll=0; ll<8; ll++) {
          int rl = (lh*8 + ll)*8 + nn;        // r_local = l_local*8 + n
          int c  = rl >> 2;
          v8[ll] = Ts[d*128 + ((c ^ ((d & 7) << 2)) << 2) + (rl & 3)];
        }
        size_t off = (((size_t)nn*12 + hh)*64 + d)*1024 + (size_t)bx*16 + lh*8;
        *(u16x8*)(vtp + off) = v8;
      }
    } else {
      // ---- q/k: fused row-normalize + scatter ----
      const int c0 = j0 - p*768;
      const int hh = c0 >> 6;
      u16* dst = (p==0) ? qh : kh;
      float qsc = 1.0f;
      if (p == 0) qsc = __expf(fminf(lsb[hh], 4.6051701859880913680f)) * 1.4426950408889634f;
#pragma unroll
      for (int mf=0; mf<4; mf++)
#pragma unroll
        for (int i=0;i<4;i++) {
          int r = r0 + mf*16 + 4*hi + i;
          int n = r & 7, l = r >> 3;
          float v[4]; float ss2 = 0.f;
#pragma unroll
          for (int nf=0;nf<4;nf++){ v[nf] = acc[mf][nf][i] + bi[nf]; ss2 += v[nf]*v[nf]; }
          ss2 += __shfl_xor(ss2, 1);
          ss2 += __shfl_xor(ss2, 2);
          ss2 += __shfl_xor(ss2, 4);
          ss2 += __shfl_xor(ss2, 8);
          float sc = qsc / fmaxf(sqrtf(ss2), 1e-12f);
          size_t base = (((size_t)n*12 + hh)*1024 + l)*64;
#pragma unroll
          for (int nf=0;nf<4;nf++)
            dst[base + nf*16 + lo] = f2h(v[nf]*sc);
        }
    }
  } else {
#pragma unroll
    for (int nf=0; nf<4; nf++) {
      int j = j0 + nf*16 + lo;
      float bi = bias[j];
#pragma unroll
      for (int mf=0; mf<4; mf++)
#pragma unroll
        for (int i=0;i<4;i++) {
          int r = r0 + mf*16 + 4*hi + i;
          outp[(size_t)r*768 + j] = acc[mf][nf][i] + bi;
        }
    }
  }
}

// ---------------- flash attention (cosine-bounded: no running max needed) ----------------
// R13 structure (32 q-rows/wave, shared K/V frags) + R14 double-buffered K/VT
// tiles -> ONE lgkm+barrier per iteration. See round-13/14 notes.
__global__ __launch_bounds__(256, 3) void flash_kernel(
    const u16* __restrict__ qh, const u16* __restrict__ kh, const u16* __restrict__ vt,
    u16* __restrict__ obuf, const float* __restrict__ hsv, const float* __restrict__ lsp)
{
  __shared__ u16 lK[2][64*64];    // [buf][k][d] swizzled 16B slots
  __shared__ u16 lVT[2][64*64];   // [buf][d][k] permuted+swizzled 8B chunks
  // XCD-locality remap: 12 heads x 8 q-tiles per XCD (3MB K+V resident in L2)
  const int lin = blockIdx.y*8 + blockIdx.x;
  const int xcd = lin & 7, g = lin >> 3;
  const int nh = xcd + 8*(g >> 3);
  const int qt = g & 7;
  const int h = nh % 12, n = nh / 12;
  const u16* Qp = qh + (size_t)nh*65536;
  const u16* Kp = kh + (size_t)nh*65536;
  const u16* Vp = vt + (size_t)nh*65536;
  const int tid = threadIdx.x, lane = tid & 63, w = tid >> 6;
  const int lo = lane & 15, hi = lane >> 4;
  const int e = lo & 7;

  // Q fragments, both q-groups: lane holds Q[q=lo(+16)][d = hi*8 + j] (+32)
  h8 qa0, qa1, qb0, qb1;
  {
    const u16* qrow = Qp + (size_t)(qt*128 + w*32 + lo)*64 + hi*8;
    qa0 = *(const h8*)qrow;          qa1 = *(const h8*)(qrow + 32);
    qb0 = *(const h8*)(qrow + 1024); qb1 = *(const h8*)(qrow + 1024 + 32);
  }
  const f32x4 zero = {0.f,0.f,0.f,0.f};
  f32x4 oA[4] = {zero,zero,zero,zero};   // O^T[d=db*16+4hi+i][q=lo]
  f32x4 oB[4] = {zero,zero,zero,zero};
  f32x4 lA4 = zero, lB4 = zero;          // row sums via ones-MFMA
  const h4 ones = {(f16)1.f,(f16)1.f,(f16)1.f,(f16)1.f};

  // fp16-overflow guard (0 for these inputs; uniform branch if ever nonzero)
  float OFF;
  {
    float b = __expf(fminf(lsp[h], 4.6051701859880913680f)) * 1.4426950408889634f;
    OFF = fmaxf(b - 15.5f, 0.f);
  }

  const int sr = tid >> 2;          // stage row (k for lK, d for lVT), 0..63
  const int c4 = tid & 3;           // stage 16B-column group
  const int sx1 = sr & 7;           // K slot16 XOR
  const int sx2 = (sr & 7) << 1;    // VT chunk8 XOR (even)

  u32x4 ka, kb, va, vb;
  ka = *(const u32x4*)(Kp + (size_t)sr*64 + c4*16);
  kb = *(const u32x4*)(Kp + (size_t)sr*64 + c4*16 + 8);
  va = *(const u32x4*)(Vp + (size_t)sr*1024 + c4*16);
  vb = *(const u32x4*)(Vp + (size_t)sr*1024 + c4*16 + 8);

#define STAGE_WRITE(bf) do { \
    u16* kr = lK[bf] + sr*64; \
    *(u32x4*)(kr + (((2*c4)   ^ sx1) << 3)) = ka; \
    *(u32x4*)(kr + (((2*c4+1) ^ sx1) << 3)) = kb; \
    u16* vr = lVT[bf] + sr*64; \
    *(u32x2*)(vr + (((( 0|c4) ^ sx2) << 2))) = (u32x2){va[0], va[1]}; \
    *(u32x2*)(vr + (((( 4|c4) ^ sx2) << 2))) = (u32x2){va[2], va[3]}; \
    *(u32x2*)(vr + (((( 8|c4) ^ sx2) << 2))) = (u32x2){vb[0], vb[1]}; \
    *(u32x2*)(vr + ((((12|c4) ^ sx2) << 2))) = (u32x2){vb[2], vb[3]}; \
  } while(0)

  STAGE_WRITE(0);
  asm volatile("s_waitcnt lgkmcnt(0)" ::: "memory");
  __builtin_amdgcn_sched_barrier(0);
  __builtin_amdgcn_s_barrier();

  for (int t = 0; t < 16; ++t) {
    const int cb = t & 1;
    if (t < 15) {  // prefetch next tile into regs; lands under this iter's compute
      ka = *(const u32x4*)(Kp + (size_t)(t+1)*4096 + (size_t)sr*64 + c4*16);
      kb = *(const u32x4*)(Kp + (size_t)(t+1)*4096 + (size_t)sr*64 + c4*16 + 8);
      va = *(const u32x4*)(Vp + (size_t)sr*1024 + (t+1)*64 + c4*16);
      vb = *(const u32x4*)(Vp + (size_t)sr*1024 + (t+1)*64 + c4*16 + 8);
    }
    // ---- S^T = K . Q^T, both q-groups (K fragments read ONCE, used twice) ----
    f32x4 sa[4], sb[4];
#pragma unroll
    for (int kf=0; kf<4; kf++) {
      const u16* krow = lK[cb] + (kf*16 + lo)*64;
      h8 k0 = *(const h8*)(krow + (((hi  ) ^ e) << 3));
      h8 k1 = *(const h8*)(krow + (((hi+4) ^ e) << 3));
      sa[kf] = MFMA32(k1, qa1, MFMA32(k0, qa0, zero));
      sb[kf] = MFMA32(k1, qb1, MFMA32(k0, qb0, zero));
    }
    if (OFF != 0.f) {
#pragma unroll
      for (int kf=0;kf<4;kf++)
#pragma unroll
        for (int i=0;i<4;i++) { sa[kf][i] -= OFF; sb[kf][i] -= OFF; }
    }
    // ---- p = exp2(s), packed into mfma16 B-operand layout ----
    h4 pa[4], pb[4];
#pragma unroll
    for (int kf=0;kf<4;kf++) {
      h2 a01 = pkrtz(fast_exp2(sa[kf][0]), fast_exp2(sa[kf][1]));
      h2 a23 = pkrtz(fast_exp2(sa[kf][2]), fast_exp2(sa[kf][3]));
      pa[kf] = __builtin_shufflevector(a01, a23, 0, 1, 2, 3);
      h2 b01 = pkrtz(fast_exp2(sb[kf][0]), fast_exp2(sb[kf][1]));
      h2 b23 = pkrtz(fast_exp2(sb[kf][2]), fast_exp2(sb[kf][3]));
      pb[kf] = __builtin_shufflevector(b01, b23, 0, 1, 2, 3);
    }
    // ---- row sums on the matrix pipe ----
#pragma unroll
    for (int kf=0;kf<4;kf++) {
      lA4 = MFMA16(ones, pa[kf], lA4);
      lB4 = MFMA16(ones, pb[kf], lB4);
    }
    // ---- PV: O^T += VT-frag x P-frag (V fragments read ONCE, used twice) ----
#pragma unroll
    for (int db=0; db<4; db++) {
      const u16* vrow = lVT[cb] + (db*16 + lo)*64;
      h8 v01 = *(const h8*)(vrow + ((((2*hi  ) ^ e) << 3)));
      h8 v23 = *(const h8*)(vrow + ((((2*hi+1) ^ e) << 3)));
      h4 f0 = __builtin_shufflevector(v01, v01, 0,1,2,3);
      h4 f1 = __builtin_shufflevector(v01, v01, 4,5,6,7);
      h4 f2 = __builtin_shufflevector(v23, v23, 0,1,2,3);
      h4 f3 = __builtin_shufflevector(v23, v23, 4,5,6,7);
      oA[db] = MFMA16(f0, pa[0], oA[db]);
      oB[db] = MFMA16(f0, pb[0], oB[db]);
      oA[db] = MFMA16(f1, pa[1], oA[db]);
      oB[db] = MFMA16(f1, pb[1], oB[db]);
      oA[db] = MFMA16(f2, pa[2], oA[db]);
      oB[db] = MFMA16(f2, pb[2], oB[db]);
      oA[db] = MFMA16(f3, pa[3], oA[db]);
      oB[db] = MFMA16(f3, pb[3], oB[db]);
    }
    // ---- write next tile into the OTHER buffer; single barrier per iter ----
    if (t < 15) STAGE_WRITE(cb ^ 1);
    asm volatile("s_waitcnt lgkmcnt(0)" ::: "memory"); // my ds_writes visible
    __builtin_amdgcn_sched_barrier(0);
    __builtin_amdgcn_s_barrier();
  }
#undef STAGE_WRITE
  // epilogue: O[q][d] = O^T / l * head_scale, store fp16 into (L,N,C)
  float hsc = hsv[h];
  float invA = hsc / lA4[0];
  float invB = hsc / lB4[0];
  int l0 = qt*128 + w*32 + lo;
  u16* dA = obuf + ((size_t)l0*8 + n)*768 + h*64;
  u16* dB = obuf + ((size_t)(l0+16)*8 + n)*768 + h*64;
#pragma unroll
  for (int db=0; db<4; db++) {
    u16x4 pk0, pk1;
#pragma unroll
    for (int i=0;i<4;i++) { pk0[i] = f2h(oA[db][i]*invA); pk1[i] = f2h(oB[db][i]*invB); }
    *(u16x4*)(dA + db*16 + hi*4) = pk0;
    *(u16x4*)(dB + db*16 + hi*4) = pk1;
  }
}

extern "C" void kernel_launch(void* const* d_in, const int* in_sizes, int n_in,
                              void* d_out, int out_size, void* d_ws, size_t ws_size,
                              hipStream_t stream)
{
  (void)in_sizes; (void)n_in; (void)out_size; (void)ws_size;
  const float* x  = (const float*)d_in[0];
  const float* w1 = (const float*)d_in[1];
  const float* b1 = (const float*)d_in[2];
  const float* ls = (const float*)d_in[3];
  const float* hs = (const float*)d_in[4];
  const float* w2 = (const float*)d_in[5];
  const float* b2 = (const float*)d_in[6];
  float* out = (float*)d_out;

  u16* x_bf  = (u16*)d_ws;            // 8192 x 768  (reused as ob after GEMM1)
  u16* w1_bf = x_bf  + 6291456;       // 2304 x 768
  u16* w2_bf = w1_bf + 1769472;       // 768 x 768
  u16* qh    = w2_bf + 589824;        // (N,H,L,D) normalized (+ls*log2e on q)
  u16* kh    = qh    + 6291456;
  u16* vt    = kh    + 6291456;       // (N,H,D,L) — written directly by gemm1
  u16* ob    = x_bf;                  // (L,N,C) fp16, aliases x_bf

  cvt3_kernel<<<8448, 256, 0, stream>>>(x, x_bf, w1, w1_bf, w2, w2_bf);
  gemm_kernel<<<dim3(64,9), 512, 0, stream>>>(x_bf, w1_bf, b1, 0, qh, kh, vt, nullptr, ls);
  flash_kernel<<<dim3(8,96), 256, 0, stream>>>(qh, kh, vt, ob, hs, ls);
  gemm_kernel<<<dim3(64,3), 512, 0, stream>>>(ob, w2_bf, b2, 1, nullptr, nullptr, nullptr, out, ls);
}